// Round 1
// baseline (882.427 us; speedup 1.0000x reference)
//
#include <hip/hip_runtime.h>
#include <hip/hip_bf16.h>

#define DEVFN static __device__ __forceinline__

typedef __attribute__((ext_vector_type(8))) __bf16 bf16x8;
typedef __attribute__((ext_vector_type(4))) float f32x4;

#define MFMA16(a, b, c) __builtin_amdgcn_mfma_f32_16x16x32_bf16(a, b, c, 0, 0, 0)

// async global->LDS, 16B per lane; dest is wave-uniform base + lane*16
DEVFN void gload16(const void* g, void* l) {
  __builtin_amdgcn_global_load_lds((const __attribute__((address_space(1))) void*)g,
                                   (__attribute__((address_space(3))) void*)l, 16, 0, 0);
}

// ---------------- f32 -> bf16 convert (vectorized) ----------------
__global__ __launch_bounds__(256) void cvt_f32_bf16(const float* __restrict__ in,
                                                    __bf16* __restrict__ out) {
  size_t i = ((size_t)blockIdx.x * 256 + threadIdx.x) * 8;
  f32x4 a = *(const f32x4*)(in + i);
  f32x4 b = *(const f32x4*)(in + i + 4);
  bf16x8 u;
  u[0] = (__bf16)a[0]; u[1] = (__bf16)a[1]; u[2] = (__bf16)a[2]; u[3] = (__bf16)a[3];
  u[4] = (__bf16)b[0]; u[5] = (__bf16)b[1]; u[6] = (__bf16)b[2]; u[7] = (__bf16)b[3];
  *(bf16x8*)(out + i) = u;
}

// ---------------- transpose f32 [K][N] -> bf16 [N][K] ----------------
__global__ __launch_bounds__(256) void transpose_w(const float* __restrict__ in,
                                                   __bf16* __restrict__ out,
                                                   int K, int N) {
  __shared__ float tile[32][33];
  const int t = threadIdx.x, tx = t & 31, ty = t >> 5;
  const int n0 = blockIdx.x * 32, k0 = blockIdx.y * 32;
#pragma unroll
  for (int r = 0; r < 4; r++)
    tile[ty + r * 8][tx] = in[(size_t)(k0 + ty + r * 8) * N + n0 + tx];
  __syncthreads();
#pragma unroll
  for (int r = 0; r < 4; r++)
    out[(size_t)(n0 + ty + r * 8) * K + k0 + tx] = (__bf16)tile[tx][ty + r * 8];
}

// ---------------- m97-structure 128x128 bf16 GEMM, C = A * Bt^T + bias ------
// MODE 0: QKV epilogue -> q (scaled by 1/sqrt(hd)*log2e), k, v   (all [BH][T][hd])
// MODE 1: f32 output epilogue
#define QK_SCALE 0.12751745f  // (1/sqrt(128)) * log2(e)

template <int MODE>
__global__ __launch_bounds__(256, 2) void gemm_bt(
    const __bf16* __restrict__ A, const __bf16* __restrict__ Bt,
    const float* __restrict__ bias, int K, int Ncols,
    __bf16* __restrict__ qo, __bf16* __restrict__ ko, __bf16* __restrict__ vo,
    float* __restrict__ outf) {
  __shared__ __align__(16) __bf16 Al[128 * 32];
  __shared__ __align__(16) __bf16 Bl[128 * 32];
  const int tid = threadIdx.x;
  const int w = tid >> 6, l = tid & 63;
  const int wr = w >> 1, wc = w & 1;
  const int lg = l >> 4, li = l & 15;
  const size_t m0 = (size_t)blockIdx.y * 128;
  const size_t n0 = (size_t)blockIdx.x * 128;

  f32x4 acc[4][4] = {};

  const __bf16* ag = A + (m0 + w * 16 + (l >> 2)) * K + (l & 3) * 8;
  const __bf16* bg = Bt + (n0 + w * 16 + (l >> 2)) * K + (l & 3) * 8;
  __bf16* al = (__bf16*)Al + w * 512;
  __bf16* bl = (__bf16*)Bl + w * 512;

  for (int k0 = 0; k0 < K; k0 += 32) {
    __syncthreads();
    gload16(ag, al);
    gload16(ag + (size_t)64 * K, al + 2048);
    gload16(bg, bl);
    gload16(bg + (size_t)64 * K, bl + 2048);
    ag += 32; bg += 32;
    __syncthreads();
    bf16x8 af[4], bf[4];
#pragma unroll
    for (int mi = 0; mi < 4; mi++)
      af[mi] = *(const bf16x8*)&Al[(wr * 64 + mi * 16 + li) * 32 + lg * 8];
#pragma unroll
    for (int ni = 0; ni < 4; ni++)
      bf[ni] = *(const bf16x8*)&Bl[(wc * 64 + ni * 16 + li) * 32 + lg * 8];
#pragma unroll
    for (int mi = 0; mi < 4; mi++)
#pragma unroll
      for (int ni = 0; ni < 4; ni++)
        acc[mi][ni] = MFMA16(af[mi], bf[ni], acc[mi][ni]);
  }

  if (MODE == 0) {
    const int which = (int)(n0 >> 11);            // 0=q 1=k 2=v (uniform per block)
    const int b = (int)(m0 >> 11);
    const int h = ((int)n0 & 2047) >> 7;
    __bf16* outp = (which == 0) ? qo : ((which == 1) ? ko : vo);
    const float scale = (which == 0) ? QK_SCALE : 1.0f;
#pragma unroll
    for (int ni = 0; ni < 4; ni++) {
      const int ncol = (int)n0 + wc * 64 + ni * 16 + li;
      const float bv = bias[ncol];
      const int d = ncol & 127;
      const size_t base = (size_t)(b * 16 + h) * 2048 * 128 + d;
#pragma unroll
      for (int mi = 0; mi < 4; mi++)
#pragma unroll
        for (int r = 0; r < 4; r++) {
          const int tt = ((int)m0 + wr * 64 + mi * 16 + lg * 4 + r) & 2047;
          outp[base + (size_t)tt * 128] = (__bf16)((acc[mi][ni][r] + bv) * scale);
        }
    }
  } else {
#pragma unroll
    for (int ni = 0; ni < 4; ni++) {
      const int ncol = (int)n0 + wc * 64 + ni * 16 + li;
      const float bv = bias[ncol];
#pragma unroll
      for (int mi = 0; mi < 4; mi++)
#pragma unroll
        for (int r = 0; r < 4; r++) {
          const size_t mrow = m0 + wr * 64 + mi * 16 + lg * 4 + r;
          outf[mrow * Ncols + ncol] = acc[mi][ni][r] + bv;
        }
    }
  }
}

// ---------------- causal flash attention ----------------
// grid: x = T/128 (q tile), y = B*H. 4 waves, each owns 32 q-rows.
// q pre-scaled by QK_SCALE -> softmax in base-2.
__global__ __launch_bounds__(256, 2) void attn_fwd(
    const __bf16* __restrict__ qb, const __bf16* __restrict__ kb,
    const __bf16* __restrict__ vb, __bf16* __restrict__ ob) {
  __shared__ __align__(16) __bf16 Kl[64 * 128];   // [key][d], col XOR-swizzled
  __shared__ __align__(16) __bf16 Vl[128 * 64];   // [d][key], key XOR-swizzled
  __shared__ __align__(16) __bf16 Pl[128 * 72];   // [qrow][key], padded stride 72
  const int qt = blockIdx.x, bh = blockIdx.y;
  const int tid = threadIdx.x;
  const int w = tid >> 6, l = tid & 63;
  const int lg = l >> 4, li = l & 15;
  const int q0 = qt * 128;
  const __bf16* qp = qb + (size_t)bh * (2048 * 128);
  const __bf16* kp = kb + (size_t)bh * (2048 * 128);
  const __bf16* vp = vb + (size_t)bh * (2048 * 128);

  // Q fragments straight from global (read once)
  bf16x8 qf[2][4];
#pragma unroll
  for (int mi = 0; mi < 2; mi++)
#pragma unroll
    for (int kk = 0; kk < 4; kk++)
      qf[mi][kk] = *(const bf16x8*)(qp + (size_t)(q0 + w * 32 + mi * 16 + li) * 128 + kk * 32 + lg * 8);

  f32x4 o[2][8] = {};
  float mrow[2][4], lrow[2][4];
#pragma unroll
  for (int mi = 0; mi < 2; mi++)
#pragma unroll
    for (int r = 0; r < 4; r++) { mrow[mi][r] = -1e30f; lrow[mi][r] = 0.f; }

  const int ntiles = 2 * qt + 2;
  for (int kt = 0; kt < ntiles; kt++) {
    const int k0 = kt * 64;
    __syncthreads();
    // K: global_load_lds, source col pre-swizzled so swizzled reads are conflict-free
#pragma unroll
    for (int i = 0; i < 4; i++) {
      const int key = i * 16 + w * 4 + lg;
      gload16(kp + (size_t)(k0 + key) * 128 + 8 * (li ^ (key & 7)),
              (__bf16*)Kl + i * 2048 + w * 512);
    }
    // V: reg-staged transpose into [d][key] with XOR swizzle on key
#pragma unroll
    for (int i = 0; i < 4; i++) {
      const int c = i * 256 + tid;
      const int row = c >> 4;            // key
      const int cc = (c & 15) * 8;       // d base
      bf16x8 tv = *(const bf16x8*)(vp + (size_t)(k0 + row) * 128 + cc);
#pragma unroll
      for (int j = 0; j < 8; j++) {
        const int d = cc + j;
        Vl[d * 64 + (row ^ ((d & 7) << 3))] = tv[j];
      }
    }
    __syncthreads();

    // S = Q K^T  (A rows = q via li, B cols = key via li)
    f32x4 s[2][4] = {};
#pragma unroll
    for (int kk = 0; kk < 4; kk++) {
      bf16x8 bk[4];
#pragma unroll
      for (int ni = 0; ni < 4; ni++) {
        const int key = ni * 16 + li;
        bk[ni] = *(const bf16x8*)&Kl[key * 128 + ((kk * 32 + lg * 8) ^ ((key & 7) << 3))];
      }
#pragma unroll
      for (int mi = 0; mi < 2; mi++)
#pragma unroll
        for (int ni = 0; ni < 4; ni++)
          s[mi][ni] = MFMA16(qf[mi][kk], bk[ni], s[mi][ni]);
    }

    const bool diag = (kt >= 2 * qt);
#pragma unroll
    for (int mi = 0; mi < 2; mi++) {
#pragma unroll
      for (int r = 0; r < 4; r++) {
        const int qrow = q0 + w * 32 + mi * 16 + lg * 4 + r;
        float vals[4];
        float vmax = -1e30f;
#pragma unroll
        for (int ni = 0; ni < 4; ni++) {
          float x = s[mi][ni][r];
          if (diag && (k0 + ni * 16 + li) > qrow) x = -1e30f;
          vals[ni] = x;
          vmax = fmaxf(vmax, x);
        }
        vmax = fmaxf(vmax, __shfl_xor(vmax, 1));
        vmax = fmaxf(vmax, __shfl_xor(vmax, 2));
        vmax = fmaxf(vmax, __shfl_xor(vmax, 4));
        vmax = fmaxf(vmax, __shfl_xor(vmax, 8));
        const float mnew = fmaxf(mrow[mi][r], vmax);
        const float sc = exp2f(mrow[mi][r] - mnew);
        mrow[mi][r] = mnew;
        float ps = 0.f;
        const int prow = w * 32 + mi * 16 + lg * 4 + r;
#pragma unroll
        for (int ni = 0; ni < 4; ni++) {
          const float p = exp2f(vals[ni] - mnew);
          ps += p;
          Pl[prow * 72 + ni * 16 + li] = (__bf16)p;
        }
        ps += __shfl_xor(ps, 1);
        ps += __shfl_xor(ps, 2);
        ps += __shfl_xor(ps, 4);
        ps += __shfl_xor(ps, 8);
        lrow[mi][r] = lrow[mi][r] * sc + ps;
#pragma unroll
        for (int nd = 0; nd < 8; nd++) o[mi][nd][r] *= sc;
      }
    }

    // O += P V   (P via LDS round-trip; V from transposed tile)
#pragma unroll
    for (int kk = 0; kk < 2; kk++) {
      bf16x8 pf[2];
#pragma unroll
      for (int mi = 0; mi < 2; mi++)
        pf[mi] = *(const bf16x8*)&Pl[(w * 32 + mi * 16 + li) * 72 + kk * 32 + lg * 8];
#pragma unroll
      for (int nd = 0; nd < 8; nd++) {
        const int d = nd * 16 + li;
        bf16x8 vf = *(const bf16x8*)&Vl[d * 64 + ((kk * 32 + lg * 8) ^ ((d & 7) << 3))];
#pragma unroll
        for (int mi = 0; mi < 2; mi++)
          o[mi][nd] = MFMA16(pf[mi], vf, o[mi][nd]);
      }
    }
  }

  const int b = bh >> 4, h = bh & 15;
#pragma unroll
  for (int mi = 0; mi < 2; mi++) {
    float inv[4];
#pragma unroll
    for (int r = 0; r < 4; r++) inv[r] = 1.0f / lrow[mi][r];
#pragma unroll
    for (int nd = 0; nd < 8; nd++)
#pragma unroll
      for (int r = 0; r < 4; r++)
        ob[(size_t)(b * 2048 + q0 + w * 32 + mi * 16 + lg * 4 + r) * 2048 + h * 128 + nd * 16 + li]
            = (__bf16)(o[mi][nd][r] * inv[r]);
  }
}

extern "C" void kernel_launch(void* const* d_in, const int* in_sizes, int n_in,
                              void* d_out, int out_size, void* d_ws, size_t ws_size,
                              hipStream_t stream) {
  (void)in_sizes; (void)n_in; (void)out_size; (void)ws_size;
  const float* x     = (const float*)d_in[0];
  const float* w_qkv = (const float*)d_in[1];
  const float* b_qkv = (const float*)d_in[2];
  const float* w_out = (const float*)d_in[3];
  const float* b_out = (const float*)d_in[4];
  float* out = (float*)d_out;
  char* ws = (char*)d_ws;

  // workspace layout (bytes); xb region is reused for attention output
  __bf16* xb    = (__bf16*)(ws + 0);           // 33554432  x as bf16, later attn out
  __bf16* wqkvT = (__bf16*)(ws + 33554432);    // 25165824  w_qkv^T bf16 [6144][2048]
  __bf16* qbuf  = (__bf16*)(ws + 58720256);    // 33554432  [B*H][T][hd]
  __bf16* kbuf  = (__bf16*)(ws + 92274688);    // 33554432
  __bf16* vbuf  = (__bf16*)(ws + 125829120);   // 33554432
  __bf16* woutT = (__bf16*)(ws + 159383552);   // 8388608   w_out^T bf16 [2048][2048]
  // total: 167772160 bytes

  cvt_f32_bf16<<<8192, 256, 0, stream>>>(x, xb);
  transpose_w<<<dim3(192, 64), 256, 0, stream>>>(w_qkv, wqkvT, 2048, 6144);
  transpose_w<<<dim3(64, 64), 256, 0, stream>>>(w_out, woutT, 2048, 2048);
  gemm_bt<0><<<dim3(48, 64), 256, 0, stream>>>(xb, wqkvT, b_qkv, 2048, 6144,
                                               qbuf, kbuf, vbuf, nullptr);
  attn_fwd<<<dim3(16, 64), 256, 0, stream>>>(qbuf, kbuf, vbuf, xb);
  gemm_bt<1><<<dim3(16, 64), 256, 0, stream>>>(xb, woutT, b_out, 2048, 2048,
                                               nullptr, nullptr, nullptr, out);
}

// Round 2
// 692.217 us; speedup vs baseline: 1.2748x; 1.2748x over previous
//
#include <hip/hip_runtime.h>
#include <hip/hip_bf16.h>

#define DEVFN static __device__ __forceinline__

typedef __attribute__((ext_vector_type(8))) __bf16 bf16x8;
typedef __attribute__((ext_vector_type(4))) float f32x4;

#define MFMA16(a, b, c) __builtin_amdgcn_mfma_f32_16x16x32_bf16(a, b, c, 0, 0, 0)

// async global->LDS, 16B per lane; dest is wave-uniform base + lane*16
DEVFN void gload16(const void* g, void* l) {
  __builtin_amdgcn_global_load_lds((const __attribute__((address_space(1))) void*)g,
                                   (__attribute__((address_space(3))) void*)l, 16, 0, 0);
}

// ---------------- f32 -> bf16 convert (vectorized) ----------------
__global__ __launch_bounds__(256) void cvt_f32_bf16(const float* __restrict__ in,
                                                    __bf16* __restrict__ out) {
  size_t i = ((size_t)blockIdx.x * 256 + threadIdx.x) * 8;
  f32x4 a = *(const f32x4*)(in + i);
  f32x4 b = *(const f32x4*)(in + i + 4);
  bf16x8 u;
  u[0] = (__bf16)a[0]; u[1] = (__bf16)a[1]; u[2] = (__bf16)a[2]; u[3] = (__bf16)a[3];
  u[4] = (__bf16)b[0]; u[5] = (__bf16)b[1]; u[6] = (__bf16)b[2]; u[7] = (__bf16)b[3];
  *(bf16x8*)(out + i) = u;
}

// ---------------- transpose f32 [K][N] -> bf16 [N][K] ----------------
__global__ __launch_bounds__(256) void transpose_w(const float* __restrict__ in,
                                                   __bf16* __restrict__ out,
                                                   int K, int N) {
  __shared__ float tile[32][33];
  const int t = threadIdx.x, tx = t & 31, ty = t >> 5;
  const int n0 = blockIdx.x * 32, k0 = blockIdx.y * 32;
#pragma unroll
  for (int r = 0; r < 4; r++)
    tile[ty + r * 8][tx] = in[(size_t)(k0 + ty + r * 8) * N + n0 + tx];
  __syncthreads();
#pragma unroll
  for (int r = 0; r < 4; r++)
    out[(size_t)(n0 + ty + r * 8) * K + k0 + tx] = (__bf16)tile[tx][ty + r * 8];
}

// ---------------- m97-structure 128x128 bf16 GEMM, C = A * Bt^T + bias ------
// MODE 0: QKV epilogue -> q (scaled by 1/sqrt(hd)*log2e), k, v   (all [BH][T][hd])
// MODE 1: f32 output epilogue
#define QK_SCALE 0.12751745f  // (1/sqrt(128)) * log2(e)

template <int MODE>
__global__ __launch_bounds__(256, 2) void gemm_bt(
    const __bf16* __restrict__ A, const __bf16* __restrict__ Bt,
    const float* __restrict__ bias, int K, int Ncols,
    __bf16* __restrict__ qo, __bf16* __restrict__ ko, __bf16* __restrict__ vo,
    float* __restrict__ outf) {
  __shared__ __align__(16) __bf16 Al[128 * 32];
  __shared__ __align__(16) __bf16 Bl[128 * 32];
  const int tid = threadIdx.x;
  const int w = tid >> 6, l = tid & 63;
  const int wr = w >> 1, wc = w & 1;
  const int lg = l >> 4, li = l & 15;
  const size_t m0 = (size_t)blockIdx.y * 128;
  const size_t n0 = (size_t)blockIdx.x * 128;

  f32x4 acc[4][4] = {};

  const __bf16* ag = A + (m0 + w * 16 + (l >> 2)) * K + (l & 3) * 8;
  const __bf16* bg = Bt + (n0 + w * 16 + (l >> 2)) * K + (l & 3) * 8;
  __bf16* al = (__bf16*)Al + w * 512;
  __bf16* bl = (__bf16*)Bl + w * 512;

  for (int k0 = 0; k0 < K; k0 += 32) {
    __syncthreads();
    gload16(ag, al);
    gload16(ag + (size_t)64 * K, al + 2048);
    gload16(bg, bl);
    gload16(bg + (size_t)64 * K, bl + 2048);
    ag += 32; bg += 32;
    __syncthreads();
    bf16x8 af[4], bf[4];
#pragma unroll
    for (int mi = 0; mi < 4; mi++)
      af[mi] = *(const bf16x8*)&Al[(wr * 64 + mi * 16 + li) * 32 + lg * 8];
#pragma unroll
    for (int ni = 0; ni < 4; ni++)
      bf[ni] = *(const bf16x8*)&Bl[(wc * 64 + ni * 16 + li) * 32 + lg * 8];
#pragma unroll
    for (int mi = 0; mi < 4; mi++)
#pragma unroll
      for (int ni = 0; ni < 4; ni++)
        acc[mi][ni] = MFMA16(af[mi], bf[ni], acc[mi][ni]);
  }

  if (MODE == 0) {
    const int which = (int)(n0 >> 11);            // 0=q 1=k 2=v (uniform per block)
    const int b = (int)(m0 >> 11);
    const int h = ((int)n0 & 2047) >> 7;
    __bf16* outp = (which == 0) ? qo : ((which == 1) ? ko : vo);
    const float scale = (which == 0) ? QK_SCALE : 1.0f;
#pragma unroll
    for (int ni = 0; ni < 4; ni++) {
      const int ncol = (int)n0 + wc * 64 + ni * 16 + li;
      const float bv = bias[ncol];
      const int d = ncol & 127;
      const size_t base = (size_t)(b * 16 + h) * 2048 * 128 + d;
#pragma unroll
      for (int mi = 0; mi < 4; mi++)
#pragma unroll
        for (int r = 0; r < 4; r++) {
          const int tt = ((int)m0 + wr * 64 + mi * 16 + lg * 4 + r) & 2047;
          outp[base + (size_t)tt * 128] = (__bf16)((acc[mi][ni][r] + bv) * scale);
        }
    }
  } else {
#pragma unroll
    for (int ni = 0; ni < 4; ni++) {
      const int ncol = (int)n0 + wc * 64 + ni * 16 + li;
      const float bv = bias[ncol];
#pragma unroll
      for (int mi = 0; mi < 4; mi++)
#pragma unroll
        for (int r = 0; r < 4; r++) {
          const size_t mrow = m0 + wr * 64 + mi * 16 + lg * 4 + r;
          outf[mrow * Ncols + ncol] = acc[mi][ni][r] + bv;
        }
    }
  }
}

// ---------------- causal flash attention ----------------
// grid: x = T/128 (q tile, DESCENDING so longest blocks launch first),
// y = B*H. 4 waves, each owns 32 q-rows. q pre-scaled by QK_SCALE.
// One KV tile step; DIAG enables per-element causal masking (last 2 tiles only).
template <bool DIAG>
DEVFN void attn_tile(int kt, int q0, int w, int lg, int li, int tid,
                     const __bf16* kp, const __bf16* vp,
                     __bf16* Kl, __bf16* Vl, __bf16* Pl,
                     const bf16x8 (&qf)[2][4], f32x4 (&o)[2][8],
                     float (&mrow)[2][4], float (&lrow)[2][4]) {
  const int k0 = kt * 64;
  __syncthreads();
  // K: global_load_lds, source col pre-swizzled -> swizzled reads conflict-free
#pragma unroll
  for (int i = 0; i < 4; i++) {
    const int key = i * 16 + w * 4 + lg;
    gload16(kp + (size_t)(k0 + key) * 128 + 8 * (li ^ (key & 7)),
            Kl + i * 2048 + w * 512);
  }
  // V: reg-staged transpose into [d][key]; swizzle s(d)=((d^(d>>3))&7)<<3 so
  // the 16 lanes sharing a key (varying d) spread across banks (was 16-way).
#pragma unroll
  for (int i = 0; i < 4; i++) {
    const int c = i * 256 + tid;
    const int row = c >> 4;            // key
    const int cc = (c & 15) * 8;       // d base
    bf16x8 tv = *(const bf16x8*)(vp + (size_t)(k0 + row) * 128 + cc);
#pragma unroll
    for (int j = 0; j < 8; j++) {
      const int sw = ((j ^ (c & 15)) & 7) << 3;
      Vl[(cc + j) * 64 + (row ^ sw)] = tv[j];
    }
  }
  __syncthreads();

  // S = Q K^T
  f32x4 s[2][4] = {};
#pragma unroll
  for (int kk = 0; kk < 4; kk++) {
    bf16x8 bk[4];
#pragma unroll
    for (int ni = 0; ni < 4; ni++) {
      const int key = ni * 16 + li;
      bk[ni] = *(const bf16x8*)&Kl[key * 128 + ((kk * 32 + lg * 8) ^ ((key & 7) << 3))];
    }
#pragma unroll
    for (int mi = 0; mi < 2; mi++)
#pragma unroll
      for (int ni = 0; ni < 4; ni++)
        s[mi][ni] = MFMA16(qf[mi][kk], bk[ni], s[mi][ni]);
  }

  // online softmax (base-2; q pre-scaled by log2e/sqrt(hd))
#pragma unroll
  for (int mi = 0; mi < 2; mi++) {
#pragma unroll
    for (int r = 0; r < 4; r++) {
      const int prow = w * 32 + mi * 16 + lg * 4 + r;
      float vals[4];
      float vmax = -1e30f;
#pragma unroll
      for (int ni = 0; ni < 4; ni++) {
        float x = s[mi][ni][r];
        if (DIAG) {
          if ((k0 + ni * 16 + li) > (q0 + prow)) x = -1e30f;
        }
        vals[ni] = x;
        vmax = fmaxf(vmax, x);
      }
      vmax = fmaxf(vmax, __shfl_xor(vmax, 1));
      vmax = fmaxf(vmax, __shfl_xor(vmax, 2));
      vmax = fmaxf(vmax, __shfl_xor(vmax, 4));
      vmax = fmaxf(vmax, __shfl_xor(vmax, 8));
      const float mnew = fmaxf(mrow[mi][r], vmax);
      const float sc = __builtin_amdgcn_exp2f(mrow[mi][r] - mnew);
      mrow[mi][r] = mnew;
      float ps = 0.f;
#pragma unroll
      for (int ni = 0; ni < 4; ni++) {
        const float p = __builtin_amdgcn_exp2f(vals[ni] - mnew);
        ps += p;
        Pl[prow * 72 + ni * 16 + li] = (__bf16)p;
      }
      ps += __shfl_xor(ps, 1);
      ps += __shfl_xor(ps, 2);
      ps += __shfl_xor(ps, 4);
      ps += __shfl_xor(ps, 8);
      lrow[mi][r] = lrow[mi][r] * sc + ps;
#pragma unroll
      for (int nd = 0; nd < 8; nd++) o[mi][nd][r] *= sc;
    }
  }

  // O += P V
#pragma unroll
  for (int kk = 0; kk < 2; kk++) {
    bf16x8 pf[2];
#pragma unroll
    for (int mi = 0; mi < 2; mi++)
      pf[mi] = *(const bf16x8*)&Pl[(w * 32 + mi * 16 + li) * 72 + kk * 32 + lg * 8];
#pragma unroll
    for (int nd = 0; nd < 8; nd++) {
      const int d = nd * 16 + li;
      const int swd = (((d & 7) ^ (d >> 3)) & 7) << 3;
      bf16x8 vf = *(const bf16x8*)&Vl[d * 64 + ((kk * 32 + lg * 8) ^ swd)];
#pragma unroll
      for (int mi = 0; mi < 2; mi++)
        o[mi][nd] = MFMA16(pf[mi], vf, o[mi][nd]);
    }
  }
}

__global__ __launch_bounds__(256, 2) void attn_fwd(
    const __bf16* __restrict__ qb, const __bf16* __restrict__ kb,
    const __bf16* __restrict__ vb, __bf16* __restrict__ ob) {
  __shared__ __align__(16) __bf16 Kl[64 * 128];   // [key][d], col XOR-swizzled
  __shared__ __align__(16) __bf16 Vl[128 * 64];   // [d][key], key XOR-swizzled by s(d)
  __shared__ __align__(16) __bf16 Pl[128 * 72];   // [qrow][key], padded stride 72
  const int qt = (int)gridDim.x - 1 - (int)blockIdx.x;  // longest blocks first
  const int bh = blockIdx.y;
  const int tid = threadIdx.x;
  const int w = tid >> 6, l = tid & 63;
  const int lg = l >> 4, li = l & 15;
  const int q0 = qt * 128;
  const __bf16* qp = qb + (size_t)bh * (2048 * 128);
  const __bf16* kp = kb + (size_t)bh * (2048 * 128);
  const __bf16* vp = vb + (size_t)bh * (2048 * 128);

  // Q fragments straight from global (read once)
  bf16x8 qf[2][4];
#pragma unroll
  for (int mi = 0; mi < 2; mi++)
#pragma unroll
    for (int kk = 0; kk < 4; kk++)
      qf[mi][kk] = *(const bf16x8*)(qp + (size_t)(q0 + w * 32 + mi * 16 + li) * 128 + kk * 32 + lg * 8);

  f32x4 o[2][8] = {};
  float mrow[2][4], lrow[2][4];
#pragma unroll
  for (int mi = 0; mi < 2; mi++)
#pragma unroll
    for (int r = 0; r < 4; r++) { mrow[mi][r] = -1e30f; lrow[mi][r] = 0.f; }

  const int nfull = 2 * qt;  // tiles fully below the diagonal: no masking
  for (int kt = 0; kt < nfull; kt++)
    attn_tile<false>(kt, q0, w, lg, li, tid, kp, vp, Kl, Vl, Pl, qf, o, mrow, lrow);
  attn_tile<true>(nfull, q0, w, lg, li, tid, kp, vp, Kl, Vl, Pl, qf, o, mrow, lrow);
  attn_tile<true>(nfull + 1, q0, w, lg, li, tid, kp, vp, Kl, Vl, Pl, qf, o, mrow, lrow);

  const int b = bh >> 4, h = bh & 15;
#pragma unroll
  for (int mi = 0; mi < 2; mi++) {
    float inv[4];
#pragma unroll
    for (int r = 0; r < 4; r++) inv[r] = 1.0f / lrow[mi][r];
#pragma unroll
    for (int nd = 0; nd < 8; nd++)
#pragma unroll
      for (int r = 0; r < 4; r++)
        ob[(size_t)(b * 2048 + q0 + w * 32 + mi * 16 + lg * 4 + r) * 2048 + h * 128 + nd * 16 + li]
            = (__bf16)(o[mi][nd][r] * inv[r]);
  }
}

extern "C" void kernel_launch(void* const* d_in, const int* in_sizes, int n_in,
                              void* d_out, int out_size, void* d_ws, size_t ws_size,
                              hipStream_t stream) {
  (void)in_sizes; (void)n_in; (void)out_size; (void)ws_size;
  const float* x     = (const float*)d_in[0];
  const float* w_qkv = (const float*)d_in[1];
  const float* b_qkv = (const float*)d_in[2];
  const float* w_out = (const float*)d_in[3];
  const float* b_out = (const float*)d_in[4];
  float* out = (float*)d_out;
  char* ws = (char*)d_ws;

  // workspace layout (bytes); xb region is reused for attention output
  __bf16* xb    = (__bf16*)(ws + 0);           // 33554432  x as bf16, later attn out
  __bf16* wqkvT = (__bf16*)(ws + 33554432);    // 25165824  w_qkv^T bf16 [6144][2048]
  __bf16* qbuf  = (__bf16*)(ws + 58720256);    // 33554432  [B*H][T][hd]
  __bf16* kbuf  = (__bf16*)(ws + 92274688);    // 33554432
  __bf16* vbuf  = (__bf16*)(ws + 125829120);   // 33554432
  __bf16* woutT = (__bf16*)(ws + 159383552);   // 8388608   w_out^T bf16 [2048][2048]
  // total: 167772160 bytes

  cvt_f32_bf16<<<8192, 256, 0, stream>>>(x, xb);
  transpose_w<<<dim3(192, 64), 256, 0, stream>>>(w_qkv, wqkvT, 2048, 6144);
  transpose_w<<<dim3(64, 64), 256, 0, stream>>>(w_out, woutT, 2048, 2048);
  gemm_bt<0><<<dim3(48, 64), 256, 0, stream>>>(xb, wqkvT, b_qkv, 2048, 6144,
                                               qbuf, kbuf, vbuf, nullptr);
  attn_fwd<<<dim3(16, 64), 256, 0, stream>>>(qbuf, kbuf, vbuf, xb);
  gemm_bt<1><<<dim3(16, 64), 256, 0, stream>>>(xb, woutT, b_out, 2048, 2048,
                                               nullptr, nullptr, nullptr, out);
}

// Round 3
// 607.642 us; speedup vs baseline: 1.4522x; 1.1392x over previous
//
#include <hip/hip_runtime.h>
#include <hip/hip_bf16.h>

#define DEVFN static __device__ __forceinline__

typedef __attribute__((ext_vector_type(8))) __bf16 bf16x8;
typedef __attribute__((ext_vector_type(4))) float f32x4;

#define MFMA16(a, b, c) __builtin_amdgcn_mfma_f32_16x16x32_bf16(a, b, c, 0, 0, 0)

// async global->LDS, 16B per lane; dest is wave-uniform base + lane*16
DEVFN void gload16(const void* g, void* l) {
  __builtin_amdgcn_global_load_lds((const __attribute__((address_space(1))) void*)g,
                                   (__attribute__((address_space(3))) void*)l, 16, 0, 0);
}

// ---------------- f32 -> bf16 convert (vectorized) ----------------
__global__ __launch_bounds__(256) void cvt_f32_bf16(const float* __restrict__ in,
                                                    __bf16* __restrict__ out) {
  size_t i = ((size_t)blockIdx.x * 256 + threadIdx.x) * 8;
  f32x4 a = *(const f32x4*)(in + i);
  f32x4 b = *(const f32x4*)(in + i + 4);
  bf16x8 u;
  u[0] = (__bf16)a[0]; u[1] = (__bf16)a[1]; u[2] = (__bf16)a[2]; u[3] = (__bf16)a[3];
  u[4] = (__bf16)b[0]; u[5] = (__bf16)b[1]; u[6] = (__bf16)b[2]; u[7] = (__bf16)b[3];
  *(bf16x8*)(out + i) = u;
}

// ---------------- transpose f32 [K][N] -> bf16 [N][K] ----------------
__global__ __launch_bounds__(256) void transpose_w(const float* __restrict__ in,
                                                   __bf16* __restrict__ out,
                                                   int K, int N) {
  __shared__ float tile[32][33];
  const int t = threadIdx.x, tx = t & 31, ty = t >> 5;
  const int n0 = blockIdx.x * 32, k0 = blockIdx.y * 32;
#pragma unroll
  for (int r = 0; r < 4; r++)
    tile[ty + r * 8][tx] = in[(size_t)(k0 + ty + r * 8) * N + n0 + tx];
  __syncthreads();
#pragma unroll
  for (int r = 0; r < 4; r++)
    out[(size_t)(n0 + ty + r * 8) * K + k0 + tx] = (__bf16)tile[tx][ty + r * 8];
}

// ---------------- transpose bf16 [bh][T][128] -> [bh][128][T] ----------------
__global__ __launch_bounds__(256) void transpose_v(const __bf16* __restrict__ in,
                                                   __bf16* __restrict__ out) {
  __shared__ __bf16 tile[64][72];
  const int bh = blockIdx.z;
  const int t0 = blockIdx.x * 64, d0 = blockIdx.y * 64;
  const int tid = threadIdx.x;
  const int r = tid >> 3, c8 = (tid & 7) * 8;
  const __bf16* ip = in + (size_t)bh * 2048 * 128;
#pragma unroll
  for (int i = 0; i < 2; i++)
    *(bf16x8*)&tile[i * 32 + r][c8] =
        *(const bf16x8*)(ip + (size_t)(t0 + i * 32 + r) * 128 + d0 + c8);
  __syncthreads();
  __bf16* op = out + (size_t)bh * 2048 * 128;
#pragma unroll
  for (int i = 0; i < 2; i++) {
    const int dd = i * 32 + r;
    bf16x8 v;
#pragma unroll
    for (int j = 0; j < 8; j++) v[j] = tile[c8 + j][dd];
    *(bf16x8*)(op + (size_t)(d0 + dd) * 2048 + t0 + c8) = v;
  }
}

// ---------------- m97-structure 128x128 bf16 GEMM, C = A * Bt^T + bias ------
#define QK_SCALE 0.12751745f  // (1/sqrt(128)) * log2(e)

template <int MODE>
__global__ __launch_bounds__(256, 2) void gemm_bt(
    const __bf16* __restrict__ A, const __bf16* __restrict__ Bt,
    const float* __restrict__ bias, int K, int Ncols,
    __bf16* __restrict__ qo, __bf16* __restrict__ ko, __bf16* __restrict__ vo,
    float* __restrict__ outf) {
  __shared__ __align__(16) __bf16 Al[128 * 32];
  __shared__ __align__(16) __bf16 Bl[128 * 32];
  const int tid = threadIdx.x;
  const int w = tid >> 6, l = tid & 63;
  const int wr = w >> 1, wc = w & 1;
  const int lg = l >> 4, li = l & 15;
  const size_t m0 = (size_t)blockIdx.y * 128;
  const size_t n0 = (size_t)blockIdx.x * 128;

  f32x4 acc[4][4] = {};

  const __bf16* ag = A + (m0 + w * 16 + (l >> 2)) * K + (l & 3) * 8;
  const __bf16* bg = Bt + (n0 + w * 16 + (l >> 2)) * K + (l & 3) * 8;
  __bf16* al = (__bf16*)Al + w * 512;
  __bf16* bl = (__bf16*)Bl + w * 512;

  for (int k0 = 0; k0 < K; k0 += 32) {
    __syncthreads();
    gload16(ag, al);
    gload16(ag + (size_t)64 * K, al + 2048);
    gload16(bg, bl);
    gload16(bg + (size_t)64 * K, bl + 2048);
    ag += 32; bg += 32;
    __syncthreads();
    bf16x8 af[4], bf[4];
#pragma unroll
    for (int mi = 0; mi < 4; mi++)
      af[mi] = *(const bf16x8*)&Al[(wr * 64 + mi * 16 + li) * 32 + lg * 8];
#pragma unroll
    for (int ni = 0; ni < 4; ni++)
      bf[ni] = *(const bf16x8*)&Bl[(wc * 64 + ni * 16 + li) * 32 + lg * 8];
#pragma unroll
    for (int mi = 0; mi < 4; mi++)
#pragma unroll
      for (int ni = 0; ni < 4; ni++)
        acc[mi][ni] = MFMA16(af[mi], bf[ni], acc[mi][ni]);
  }

  if (MODE == 0) {
    const int which = (int)(n0 >> 11);            // 0=q 1=k 2=v (uniform per block)
    const int b = (int)(m0 >> 11);
    const int h = ((int)n0 & 2047) >> 7;
    __bf16* outp = (which == 0) ? qo : ((which == 1) ? ko : vo);
    const float scale = (which == 0) ? QK_SCALE : 1.0f;
#pragma unroll
    for (int ni = 0; ni < 4; ni++) {
      const int ncol = (int)n0 + wc * 64 + ni * 16 + li;
      const float bv = bias[ncol];
      const int d = ncol & 127;
      const size_t base = (size_t)(b * 16 + h) * 2048 * 128 + d;
#pragma unroll
      for (int mi = 0; mi < 4; mi++)
#pragma unroll
        for (int r = 0; r < 4; r++) {
          const int tt = ((int)m0 + wr * 64 + mi * 16 + lg * 4 + r) & 2047;
          outp[base + (size_t)tt * 128] = (__bf16)((acc[mi][ni][r] + bv) * scale);
        }
    }
  } else {
#pragma unroll
    for (int ni = 0; ni < 4; ni++) {
      const int ncol = (int)n0 + wc * 64 + ni * 16 + li;
      const float bv = bias[ncol];
#pragma unroll
      for (int mi = 0; mi < 4; mi++)
#pragma unroll
        for (int r = 0; r < 4; r++) {
          const size_t mrow = m0 + wr * 64 + mi * 16 + lg * 4 + r;
          outf[mrow * Ncols + ncol] = acc[mi][ni][r] + bv;
        }
    }
  }
}

// ---------------- causal flash attention ----------------
// grid: x = T/128 (q tile, DESCENDING), y = B*H. 4 waves, 32 q-rows each.
// K staged [key][d] col-swizzled; V pre-transposed in global ([bh][d][T]),
// staged [d][key] with key-granule swizzle s(d) = ((d^(d>>3))&7).
// Both use global_load_lds with linear dest + inverse-swizzled SOURCE.
template <bool DIAG>
DEVFN void attn_tile(int kt, int q0, int w, int lg, int li,
                     const __bf16* const (&ksrc)[4], const __bf16* const (&vsrc)[4],
                     __bf16* Kl, __bf16* Vl, __bf16* Pl,
                     const bf16x8 (&qf)[2][4], f32x4 (&o)[2][8],
                     float (&mrow)[2][4], float (&lrow)[2][4]) {
  const int k0 = kt * 64;
  __syncthreads();
#pragma unroll
  for (int i = 0; i < 4; i++)
    gload16(ksrc[i] + (size_t)k0 * 128, Kl + i * 2048 + w * 512);
#pragma unroll
  for (int i = 0; i < 4; i++)
    gload16(vsrc[i] + k0, Vl + i * 2048 + w * 512);
  __syncthreads();

  // S = Q K^T
  f32x4 s[2][4] = {};
#pragma unroll
  for (int kk = 0; kk < 4; kk++) {
    bf16x8 bk[4];
#pragma unroll
    for (int ni = 0; ni < 4; ni++) {
      const int key = ni * 16 + li;
      bk[ni] = *(const bf16x8*)&Kl[key * 128 + ((kk * 32 + lg * 8) ^ ((key & 7) << 3))];
    }
#pragma unroll
    for (int mi = 0; mi < 2; mi++)
#pragma unroll
      for (int ni = 0; ni < 4; ni++)
        s[mi][ni] = MFMA16(qf[mi][kk], bk[ni], s[mi][ni]);
  }

  // online softmax (base-2) with defer-max: skip O-rescale unless max grew >8
#pragma unroll
  for (int mi = 0; mi < 2; mi++) {
#pragma unroll
    for (int r = 0; r < 4; r++) {
      const int prow = w * 32 + mi * 16 + lg * 4 + r;
      float vals[4];
#pragma unroll
      for (int ni = 0; ni < 4; ni++) {
        float x = s[mi][ni][r];
        if (DIAG) {
          if ((k0 + ni * 16 + li) > (q0 + prow)) x = -1e30f;
        }
        vals[ni] = x;
      }
      float vmax = fmaxf(fmaxf(vals[0], vals[1]), fmaxf(vals[2], vals[3]));
      vmax = fmaxf(vmax, __shfl_xor(vmax, 1));
      vmax = fmaxf(vmax, __shfl_xor(vmax, 2));
      vmax = fmaxf(vmax, __shfl_xor(vmax, 4));
      vmax = fmaxf(vmax, __shfl_xor(vmax, 8));
      float mref = mrow[mi][r];
      if (vmax - mref > 8.0f) {          // uniform across the 16-lane group
        const float sc = __builtin_amdgcn_exp2f(mref - vmax);
        lrow[mi][r] *= sc;
#pragma unroll
        for (int nd = 0; nd < 8; nd++) o[mi][nd][r] *= sc;
        mrow[mi][r] = vmax;
        mref = vmax;
      }
      float ps = 0.f;
#pragma unroll
      for (int ni = 0; ni < 4; ni++) {
        const float p = __builtin_amdgcn_exp2f(vals[ni] - mref);
        ps += p;
        Pl[prow * 72 + ni * 16 + li] = (__bf16)p;
      }
      ps += __shfl_xor(ps, 1);
      ps += __shfl_xor(ps, 2);
      ps += __shfl_xor(ps, 4);
      ps += __shfl_xor(ps, 8);
      lrow[mi][r] += ps;
    }
  }

  // O += P V
#pragma unroll
  for (int kk = 0; kk < 2; kk++) {
    bf16x8 pf[2];
#pragma unroll
    for (int mi = 0; mi < 2; mi++)
      pf[mi] = *(const bf16x8*)&Pl[(w * 32 + mi * 16 + li) * 72 + kk * 32 + lg * 8];
#pragma unroll
    for (int nd = 0; nd < 8; nd++) {
      const int d = nd * 16 + li;
      const int swd = ((d ^ (d >> 3)) & 7) << 3;
      bf16x8 vf = *(const bf16x8*)&Vl[d * 64 + ((kk * 32 + lg * 8) ^ swd)];
#pragma unroll
      for (int mi = 0; mi < 2; mi++)
        o[mi][nd] = MFMA16(pf[mi], vf, o[mi][nd]);
    }
  }
}

__global__ __launch_bounds__(256, 2) void attn_fwd(
    const __bf16* __restrict__ qb, const __bf16* __restrict__ kb,
    const __bf16* __restrict__ vtb, __bf16* __restrict__ ob) {
  __shared__ __align__(16) __bf16 Kl[64 * 128];   // [key][d], col XOR-swizzled
  __shared__ __align__(16) __bf16 Vl[128 * 64];   // [d][key], key-granule swizzled
  __shared__ __align__(16) __bf16 Pl[128 * 72];   // [qrow][key], padded stride 72
  const int qt = (int)gridDim.x - 1 - (int)blockIdx.x;  // longest blocks first
  const int bh = blockIdx.y;
  const int tid = threadIdx.x;
  const int w = tid >> 6, l = tid & 63;
  const int lg = l >> 4, li = l & 15;
  const int q0 = qt * 128;
  const __bf16* qp = qb + (size_t)bh * (2048 * 128);
  const __bf16* kp = kb + (size_t)bh * (2048 * 128);
  const __bf16* vtp = vtb + (size_t)bh * (2048 * 128);

  // per-lane staging source pointers (k0 added per tile)
  const __bf16* ksrc[4];
  const __bf16* vsrc[4];
#pragma unroll
  for (int i = 0; i < 4; i++) {
    const int key = i * 16 + w * 4 + lg;               // K: [key][d] rows
    ksrc[i] = kp + (size_t)key * 128 + 8 * (li ^ (key & 7));
    const int d = i * 32 + (tid >> 3);                 // V^T: [d][T] rows
    const int g = (tid & 7) ^ ((d ^ (d >> 3)) & 7);    // inverse-swizzled granule
    vsrc[i] = vtp + (size_t)d * 2048 + g * 8;
  }

  // Q fragments straight from global (read once)
  bf16x8 qf[2][4];
#pragma unroll
  for (int mi = 0; mi < 2; mi++)
#pragma unroll
    for (int kk = 0; kk < 4; kk++)
      qf[mi][kk] = *(const bf16x8*)(qp + (size_t)(q0 + w * 32 + mi * 16 + li) * 128 + kk * 32 + lg * 8);

  f32x4 o[2][8] = {};
  float mrow[2][4], lrow[2][4];
#pragma unroll
  for (int mi = 0; mi < 2; mi++)
#pragma unroll
    for (int r = 0; r < 4; r++) { mrow[mi][r] = -1e30f; lrow[mi][r] = 0.f; }

  const int nfull = 2 * qt;  // tiles fully below the diagonal: no masking
  for (int kt = 0; kt < nfull; kt++)
    attn_tile<false>(kt, q0, w, lg, li, ksrc, vsrc, Kl, Vl, Pl, qf, o, mrow, lrow);
  attn_tile<true>(nfull, q0, w, lg, li, ksrc, vsrc, Kl, Vl, Pl, qf, o, mrow, lrow);
  attn_tile<true>(nfull + 1, q0, w, lg, li, ksrc, vsrc, Kl, Vl, Pl, qf, o, mrow, lrow);

  const int b = bh >> 4, h = bh & 15;
#pragma unroll
  for (int mi = 0; mi < 2; mi++) {
    float inv[4];
#pragma unroll
    for (int r = 0; r < 4; r++) inv[r] = 1.0f / lrow[mi][r];
#pragma unroll
    for (int nd = 0; nd < 8; nd++)
#pragma unroll
      for (int r = 0; r < 4; r++)
        ob[(size_t)(b * 2048 + q0 + w * 32 + mi * 16 + lg * 4 + r) * 2048 + h * 128 + nd * 16 + li]
            = (__bf16)(o[mi][nd][r] * inv[r]);
  }
}

extern "C" void kernel_launch(void* const* d_in, const int* in_sizes, int n_in,
                              void* d_out, int out_size, void* d_ws, size_t ws_size,
                              hipStream_t stream) {
  (void)in_sizes; (void)n_in; (void)out_size; (void)ws_size;
  const float* x     = (const float*)d_in[0];
  const float* w_qkv = (const float*)d_in[1];
  const float* b_qkv = (const float*)d_in[2];
  const float* w_out = (const float*)d_in[3];
  const float* b_out = (const float*)d_in[4];
  float* out = (float*)d_out;
  char* ws = (char*)d_ws;

  // workspace layout (bytes):
  //  xb: x-bf16 for QKV GEMM, then reused as V^T [bh][128][T]
  //  vbuf: V from GEMM, then reused as attention output [B*T][C]
  __bf16* xb    = (__bf16*)(ws + 0);           // 33554432
  __bf16* wqkvT = (__bf16*)(ws + 33554432);    // 25165824  w_qkv^T bf16 [6144][2048]
  __bf16* qbuf  = (__bf16*)(ws + 58720256);    // 33554432  [B*H][T][hd]
  __bf16* kbuf  = (__bf16*)(ws + 92274688);    // 33554432
  __bf16* vbuf  = (__bf16*)(ws + 125829120);   // 33554432
  __bf16* woutT = (__bf16*)(ws + 159383552);   // 8388608   w_out^T bf16 [2048][2048]
  // total: 167772160 bytes

  cvt_f32_bf16<<<8192, 256, 0, stream>>>(x, xb);
  transpose_w<<<dim3(192, 64), 256, 0, stream>>>(w_qkv, wqkvT, 2048, 6144);
  transpose_w<<<dim3(64, 64), 256, 0, stream>>>(w_out, woutT, 2048, 2048);
  gemm_bt<0><<<dim3(48, 64), 256, 0, stream>>>(xb, wqkvT, b_qkv, 2048, 6144,
                                               qbuf, kbuf, vbuf, nullptr);
  transpose_v<<<dim3(32, 2, 64), 256, 0, stream>>>(vbuf, xb);   // xb := V^T
  attn_fwd<<<dim3(16, 64), 256, 0, stream>>>(qbuf, kbuf, xb, vbuf);  // vbuf := attn out
  gemm_bt<1><<<dim3(16, 64), 256, 0, stream>>>(vbuf, woutT, b_out, 2048, 2048,
                                               nullptr, nullptr, nullptr, out);
}

// Round 4
// 559.992 us; speedup vs baseline: 1.5758x; 1.0851x over previous
//
#include <hip/hip_runtime.h>
#include <hip/hip_bf16.h>

#define DEVFN static __device__ __forceinline__

typedef __attribute__((ext_vector_type(8))) __bf16 bf16x8;
typedef __attribute__((ext_vector_type(4))) float f32x4;

#define MFMA16(a, b, c) __builtin_amdgcn_mfma_f32_16x16x32_bf16(a, b, c, 0, 0, 0)

// async global->LDS, 16B per lane; dest is wave-uniform base + lane*16
DEVFN void gload16(const void* g, void* l) {
  __builtin_amdgcn_global_load_lds((const __attribute__((address_space(1))) void*)g,
                                   (__attribute__((address_space(3))) void*)l, 16, 0, 0);
}

DEVFN void vwait8() { asm volatile("s_waitcnt vmcnt(8)" ::: "memory"); __builtin_amdgcn_sched_barrier(0); }
DEVFN void vwait0() { asm volatile("s_waitcnt vmcnt(0)" ::: "memory"); __builtin_amdgcn_sched_barrier(0); }
DEVFN void lgk0()   { asm volatile("s_waitcnt lgkmcnt(0)" ::: "memory"); __builtin_amdgcn_sched_barrier(0); }
DEVFN void bar()    { __builtin_amdgcn_s_barrier(); }

// ---------------- f32 -> bf16 convert (vectorized) ----------------
__global__ __launch_bounds__(256) void cvt_f32_bf16(const float* __restrict__ in,
                                                    __bf16* __restrict__ out) {
  size_t i = ((size_t)blockIdx.x * 256 + threadIdx.x) * 8;
  f32x4 a = *(const f32x4*)(in + i);
  f32x4 b = *(const f32x4*)(in + i + 4);
  bf16x8 u;
  u[0] = (__bf16)a[0]; u[1] = (__bf16)a[1]; u[2] = (__bf16)a[2]; u[3] = (__bf16)a[3];
  u[4] = (__bf16)b[0]; u[5] = (__bf16)b[1]; u[6] = (__bf16)b[2]; u[7] = (__bf16)b[3];
  *(bf16x8*)(out + i) = u;
}

// ---------------- transpose f32 [K][N] -> bf16 [N][K] ----------------
__global__ __launch_bounds__(256) void transpose_w(const float* __restrict__ in,
                                                   __bf16* __restrict__ out,
                                                   int K, int N) {
  __shared__ float tile[32][33];
  const int t = threadIdx.x, tx = t & 31, ty = t >> 5;
  const int n0 = blockIdx.x * 32, k0 = blockIdx.y * 32;
#pragma unroll
  for (int r = 0; r < 4; r++)
    tile[ty + r * 8][tx] = in[(size_t)(k0 + ty + r * 8) * N + n0 + tx];
  __syncthreads();
#pragma unroll
  for (int r = 0; r < 4; r++)
    out[(size_t)(n0 + ty + r * 8) * K + k0 + tx] = (__bf16)tile[tx][ty + r * 8];
}

// ---------------- transpose bf16 [bh][T][128] -> [bh][128][T] ----------------
__global__ __launch_bounds__(256) void transpose_v(const __bf16* __restrict__ in,
                                                   __bf16* __restrict__ out) {
  __shared__ __bf16 tile[64][72];
  const int bh = blockIdx.z;
  const int t0 = blockIdx.x * 64, d0 = blockIdx.y * 64;
  const int tid = threadIdx.x;
  const int r = tid >> 3, c8 = (tid & 7) * 8;
  const __bf16* ip = in + (size_t)bh * 2048 * 128;
#pragma unroll
  for (int i = 0; i < 2; i++)
    *(bf16x8*)&tile[i * 32 + r][c8] =
        *(const bf16x8*)(ip + (size_t)(t0 + i * 32 + r) * 128 + d0 + c8);
  __syncthreads();
  __bf16* op = out + (size_t)bh * 2048 * 128;
#pragma unroll
  for (int i = 0; i < 2; i++) {
    const int dd = i * 32 + r;
    bf16x8 v;
#pragma unroll
    for (int j = 0; j < 8; j++) v[j] = tile[c8 + j][dd];
    *(bf16x8*)(op + (size_t)(d0 + dd) * 2048 + t0 + c8) = v;
  }
}

// ================= 256x256 8-phase bf16 GEMM (m201 template) =================
// 512 threads = 8 waves (2M x 4N); BK=64; LDS 128KB double-buffered.
// Tiles stored [256][64] bf16 with per-row 16B-granule XOR swizzle:
//   LDS(row, g) holds global granule g ^ (row&7).
// Staged via global_load_lds (linear dest, inverse-swizzled per-lane source).
#define QK_SCALE 0.12751745f  // (1/sqrt(128)) * log2(e)

DEVFN void stage_tile(const __bf16* gx, size_t Kst, int t, __bf16* ldst,
                      int rr, int gsw, int w) {
#pragma unroll
  for (int j = 0; j < 4; j++)
    gload16(gx + (size_t)(j * 64 + rr) * Kst + (size_t)t * 64 + gsw,
            ldst + j * 4096 + w * 512);
}

DEVFN void tile_step(__bf16* la, __bf16* lb, f32x4 (&acc)[8][4],
                     const __bf16* ga, const __bf16* gb, size_t Kst, int t, int NT,
                     int rr, int gsw, int w, int wr, int wc, int lg, int li) {
  bf16x8 a[4][2], bl[2][2], br[2][2];
  const int sa = li & 7;
  const int arow = wr * 128 + li;
  const int brow = wc * 64 + li;

  // ---- phase 1: read A(mi0-3) + B(ni0-1); MFMA quadrant (mi0-3 x ni0-1)
#pragma unroll
  for (int mi = 0; mi < 4; mi++)
#pragma unroll
    for (int ks = 0; ks < 2; ks++)
      a[mi][ks] = *(const bf16x8*)&la[(arow + mi * 16) * 64 + (((ks * 4 + lg) ^ sa) * 8)];
#pragma unroll
  for (int ni = 0; ni < 2; ni++)
#pragma unroll
    for (int ks = 0; ks < 2; ks++)
      bl[ni][ks] = *(const bf16x8*)&lb[(brow + ni * 16) * 64 + (((ks * 4 + lg) ^ sa) * 8)];
  bar();
  lgk0();
  __builtin_amdgcn_s_setprio(1);
#pragma unroll
  for (int mi = 0; mi < 4; mi++)
#pragma unroll
    for (int ni = 0; ni < 2; ni++)
#pragma unroll
      for (int ks = 0; ks < 2; ks++)
        acc[mi][ni] = MFMA16(a[mi][ks], bl[ni][ks], acc[mi][ni]);
  __builtin_amdgcn_s_setprio(0);
  bar();

  // ---- phase 2: read B(ni2-3); MFMA (mi0-3 x ni2-3)
#pragma unroll
  for (int ni = 0; ni < 2; ni++)
#pragma unroll
    for (int ks = 0; ks < 2; ks++)
      br[ni][ks] = *(const bf16x8*)&lb[(brow + (ni + 2) * 16) * 64 + (((ks * 4 + lg) ^ sa) * 8)];
  bar();
  lgk0();
  __builtin_amdgcn_s_setprio(1);
#pragma unroll
  for (int mi = 0; mi < 4; mi++)
#pragma unroll
    for (int ni = 0; ni < 2; ni++)
#pragma unroll
      for (int ks = 0; ks < 2; ks++)
        acc[mi][ni + 2] = MFMA16(a[mi][ks], br[ni][ks], acc[mi][ni + 2]);
  __builtin_amdgcn_s_setprio(0);
  bar();

  // ---- phase 3: read A(mi4-7); MFMA (mi4-7 x ni0-1)
#pragma unroll
  for (int mi = 0; mi < 4; mi++)
#pragma unroll
    for (int ks = 0; ks < 2; ks++)
      a[mi][ks] = *(const bf16x8*)&la[(arow + (mi + 4) * 16) * 64 + (((ks * 4 + lg) ^ sa) * 8)];
  bar();
  lgk0();
  __builtin_amdgcn_s_setprio(1);
#pragma unroll
  for (int mi = 0; mi < 4; mi++)
#pragma unroll
    for (int ni = 0; ni < 2; ni++)
#pragma unroll
      for (int ks = 0; ks < 2; ks++)
        acc[mi + 4][ni] = MFMA16(a[mi][ks], bl[ni][ks], acc[mi + 4][ni]);
  __builtin_amdgcn_s_setprio(0);
  bar();   // <- all waves' reads of this buffer are complete past this point

  // ---- phase 4: stage tile t+2 into THIS buffer (safe: reads all done);
  //      MFMA (mi4-7 x ni2-3). Loads stay in flight across the barrier (T4).
  if (t + 2 < NT) {
    stage_tile(ga, Kst, t + 2, la, rr, gsw, w);
    stage_tile(gb, Kst, t + 2, lb, rr, gsw, w);
  }
  __builtin_amdgcn_s_setprio(1);
#pragma unroll
  for (int mi = 0; mi < 4; mi++)
#pragma unroll
    for (int ni = 0; ni < 2; ni++)
#pragma unroll
      for (int ks = 0; ks < 2; ks++)
        acc[mi + 4][ni + 2] = MFMA16(a[mi][ks], br[ni][ks], acc[mi + 4][ni + 2]);
  __builtin_amdgcn_s_setprio(0);

  // ---- bottom: retire previous tile's stage (leave t+2's in flight)
  if (t + 2 < NT) vwait8(); else vwait0();
  bar();
}

template <int MODE>
__global__ __launch_bounds__(512, 2) void gemm256(
    const __bf16* __restrict__ A, const __bf16* __restrict__ Bt,
    const float* __restrict__ bias, int K, int Ncols,
    __bf16* __restrict__ qo, __bf16* __restrict__ ko, __bf16* __restrict__ vo,
    float* __restrict__ outf) {
  __shared__ __align__(16) __bf16 lds[65536];   // 128 KB: A0,A1,B0,B1 x 16384
  const int tid = threadIdx.x;
  const int w = tid >> 6, lane = tid & 63;
  const int wr = w >> 2, wc = w & 3;
  const int lg = lane >> 4, li = lane & 15;
  const size_t m0 = (size_t)blockIdx.y * 256;
  const size_t n0 = (size_t)blockIdx.x * 256;
  const int rr = tid >> 3;
  const int gsw = ((tid & 7) ^ (rr & 7)) * 8;
  const __bf16* ga = A + m0 * K;
  const __bf16* gb = Bt + n0 * K;
  const int NT = K >> 6;

  __bf16* la0 = lds;
  __bf16* la1 = lds + 16384;
  __bf16* lb0 = lds + 32768;
  __bf16* lb1 = lds + 49152;

  f32x4 acc[8][4] = {};

  // prologue: stage tiles 0 and 1; wait tile 0 only
  stage_tile(ga, K, 0, la0, rr, gsw, w);
  stage_tile(gb, K, 0, lb0, rr, gsw, w);
  stage_tile(ga, K, 1, la1, rr, gsw, w);
  stage_tile(gb, K, 1, lb1, rr, gsw, w);
  vwait8();
  bar();

  for (int t = 0; t < NT; t += 2) {
    tile_step(la0, lb0, acc, ga, gb, K, t,     NT, rr, gsw, w, wr, wc, lg, li);
    tile_step(la1, lb1, acc, ga, gb, K, t + 1, NT, rr, gsw, w, wr, wc, lg, li);
  }

  if (MODE == 0) {
    const int which = (int)(n0 >> 11);            // 0=q 1=k 2=v (uniform per block)
    const int b = (int)(m0 >> 11);
    __bf16* outp = (which == 0) ? qo : ((which == 1) ? ko : vo);
    const float scale = (which == 0) ? QK_SCALE : 1.0f;
#pragma unroll
    for (int ni = 0; ni < 4; ni++) {
      const int ncol = (int)n0 + wc * 64 + ni * 16 + li;
      const float bv = bias[ncol];
      const int h = (ncol & 2047) >> 7;
      const int d = ncol & 127;
      const size_t base = (size_t)(b * 16 + h) * (2048 * 128) + d;
#pragma unroll
      for (int mi = 0; mi < 8; mi++)
#pragma unroll
        for (int r = 0; r < 4; r++) {
          const int tt = ((int)m0 + wr * 128 + mi * 16 + lg * 4 + r) & 2047;
          outp[base + (size_t)tt * 128] = (__bf16)((acc[mi][ni][r] + bv) * scale);
        }
    }
  } else {
#pragma unroll
    for (int ni = 0; ni < 4; ni++) {
      const int ncol = (int)n0 + wc * 64 + ni * 16 + li;
      const float bv = bias[ncol];
#pragma unroll
      for (int mi = 0; mi < 8; mi++)
#pragma unroll
        for (int r = 0; r < 4; r++) {
          const size_t mrow = m0 + wr * 128 + mi * 16 + lg * 4 + r;
          outf[mrow * Ncols + ncol] = acc[mi][ni][r] + bv;
        }
    }
  }
}

// ---------------- causal flash attention (unchanged from R3) ----------------
template <bool DIAG>
DEVFN void attn_tile(int kt, int q0, int w, int lg, int li,
                     const __bf16* const (&ksrc)[4], const __bf16* const (&vsrc)[4],
                     __bf16* Kl, __bf16* Vl, __bf16* Pl,
                     const bf16x8 (&qf)[2][4], f32x4 (&o)[2][8],
                     float (&mrow)[2][4], float (&lrow)[2][4]) {
  const int k0 = kt * 64;
  __syncthreads();
#pragma unroll
  for (int i = 0; i < 4; i++)
    gload16(ksrc[i] + (size_t)k0 * 128, Kl + i * 2048 + w * 512);
#pragma unroll
  for (int i = 0; i < 4; i++)
    gload16(vsrc[i] + k0, Vl + i * 2048 + w * 512);
  __syncthreads();

  // S = Q K^T
  f32x4 s[2][4] = {};
#pragma unroll
  for (int kk = 0; kk < 4; kk++) {
    bf16x8 bk[4];
#pragma unroll
    for (int ni = 0; ni < 4; ni++) {
      const int key = ni * 16 + li;
      bk[ni] = *(const bf16x8*)&Kl[key * 128 + ((kk * 32 + lg * 8) ^ ((key & 7) << 3))];
    }
#pragma unroll
    for (int mi = 0; mi < 2; mi++)
#pragma unroll
      for (int ni = 0; ni < 4; ni++)
        s[mi][ni] = MFMA16(qf[mi][kk], bk[ni], s[mi][ni]);
  }

  // online softmax (base-2) with defer-max
#pragma unroll
  for (int mi = 0; mi < 2; mi++) {
#pragma unroll
    for (int r = 0; r < 4; r++) {
      const int prow = w * 32 + mi * 16 + lg * 4 + r;
      float vals[4];
#pragma unroll
      for (int ni = 0; ni < 4; ni++) {
        float x = s[mi][ni][r];
        if (DIAG) {
          if ((k0 + ni * 16 + li) > (q0 + prow)) x = -1e30f;
        }
        vals[ni] = x;
      }
      float vmax = fmaxf(fmaxf(vals[0], vals[1]), fmaxf(vals[2], vals[3]));
      vmax = fmaxf(vmax, __shfl_xor(vmax, 1));
      vmax = fmaxf(vmax, __shfl_xor(vmax, 2));
      vmax = fmaxf(vmax, __shfl_xor(vmax, 4));
      vmax = fmaxf(vmax, __shfl_xor(vmax, 8));
      float mref = mrow[mi][r];
      if (vmax - mref > 8.0f) {
        const float sc = __builtin_amdgcn_exp2f(mref - vmax);
        lrow[mi][r] *= sc;
#pragma unroll
        for (int nd = 0; nd < 8; nd++) o[mi][nd][r] *= sc;
        mrow[mi][r] = vmax;
        mref = vmax;
      }
      float ps = 0.f;
#pragma unroll
      for (int ni = 0; ni < 4; ni++) {
        const float p = __builtin_amdgcn_exp2f(vals[ni] - mref);
        ps += p;
        Pl[prow * 72 + ni * 16 + li] = (__bf16)p;
      }
      ps += __shfl_xor(ps, 1);
      ps += __shfl_xor(ps, 2);
      ps += __shfl_xor(ps, 4);
      ps += __shfl_xor(ps, 8);
      lrow[mi][r] += ps;
    }
  }

  // O += P V
#pragma unroll
  for (int kk = 0; kk < 2; kk++) {
    bf16x8 pf[2];
#pragma unroll
    for (int mi = 0; mi < 2; mi++)
      pf[mi] = *(const bf16x8*)&Pl[(w * 32 + mi * 16 + li) * 72 + kk * 32 + lg * 8];
#pragma unroll
    for (int nd = 0; nd < 8; nd++) {
      const int d = nd * 16 + li;
      const int swd = ((d ^ (d >> 3)) & 7) << 3;
      bf16x8 vf = *(const bf16x8*)&Vl[d * 64 + ((kk * 32 + lg * 8) ^ swd)];
#pragma unroll
      for (int mi = 0; mi < 2; mi++)
        o[mi][nd] = MFMA16(pf[mi], vf, o[mi][nd]);
    }
  }
}

__global__ __launch_bounds__(256, 2) void attn_fwd(
    const __bf16* __restrict__ qb, const __bf16* __restrict__ kb,
    const __bf16* __restrict__ vtb, __bf16* __restrict__ ob) {
  __shared__ __align__(16) __bf16 Kl[64 * 128];
  __shared__ __align__(16) __bf16 Vl[128 * 64];
  __shared__ __align__(16) __bf16 Pl[128 * 72];
  const int qt = (int)gridDim.x - 1 - (int)blockIdx.x;  // longest blocks first
  const int bh = blockIdx.y;
  const int tid = threadIdx.x;
  const int w = tid >> 6, l = tid & 63;
  const int lg = l >> 4, li = l & 15;
  const int q0 = qt * 128;
  const __bf16* qp = qb + (size_t)bh * (2048 * 128);
  const __bf16* kp = kb + (size_t)bh * (2048 * 128);
  const __bf16* vtp = vtb + (size_t)bh * (2048 * 128);

  const __bf16* ksrc[4];
  const __bf16* vsrc[4];
#pragma unroll
  for (int i = 0; i < 4; i++) {
    const int key = i * 16 + w * 4 + lg;
    ksrc[i] = kp + (size_t)key * 128 + 8 * (li ^ (key & 7));
    const int d = i * 32 + (tid >> 3);
    const int g = (tid & 7) ^ ((d ^ (d >> 3)) & 7);
    vsrc[i] = vtp + (size_t)d * 2048 + g * 8;
  }

  bf16x8 qf[2][4];
#pragma unroll
  for (int mi = 0; mi < 2; mi++)
#pragma unroll
    for (int kk = 0; kk < 4; kk++)
      qf[mi][kk] = *(const bf16x8*)(qp + (size_t)(q0 + w * 32 + mi * 16 + li) * 128 + kk * 32 + lg * 8);

  f32x4 o[2][8] = {};
  float mrow[2][4], lrow[2][4];
#pragma unroll
  for (int mi = 0; mi < 2; mi++)
#pragma unroll
    for (int r = 0; r < 4; r++) { mrow[mi][r] = -1e30f; lrow[mi][r] = 0.f; }

  const int nfull = 2 * qt;
  for (int kt = 0; kt < nfull; kt++)
    attn_tile<false>(kt, q0, w, lg, li, ksrc, vsrc, Kl, Vl, Pl, qf, o, mrow, lrow);
  attn_tile<true>(nfull, q0, w, lg, li, ksrc, vsrc, Kl, Vl, Pl, qf, o, mrow, lrow);
  attn_tile<true>(nfull + 1, q0, w, lg, li, ksrc, vsrc, Kl, Vl, Pl, qf, o, mrow, lrow);

  const int b = bh >> 4, h = bh & 15;
#pragma unroll
  for (int mi = 0; mi < 2; mi++) {
    float inv[4];
#pragma unroll
    for (int r = 0; r < 4; r++) inv[r] = 1.0f / lrow[mi][r];
#pragma unroll
    for (int nd = 0; nd < 8; nd++)
#pragma unroll
      for (int r = 0; r < 4; r++)
        ob[(size_t)(b * 2048 + q0 + w * 32 + mi * 16 + lg * 4 + r) * 2048 + h * 128 + nd * 16 + li]
            = (__bf16)(o[mi][nd][r] * inv[r]);
  }
}

extern "C" void kernel_launch(void* const* d_in, const int* in_sizes, int n_in,
                              void* d_out, int out_size, void* d_ws, size_t ws_size,
                              hipStream_t stream) {
  (void)in_sizes; (void)n_in; (void)out_size; (void)ws_size;
  const float* x     = (const float*)d_in[0];
  const float* w_qkv = (const float*)d_in[1];
  const float* b_qkv = (const float*)d_in[2];
  const float* w_out = (const float*)d_in[3];
  const float* b_out = (const float*)d_in[4];
  float* out = (float*)d_out;
  char* ws = (char*)d_ws;

  __bf16* xb    = (__bf16*)(ws + 0);           // x-bf16, later V^T
  __bf16* wqkvT = (__bf16*)(ws + 33554432);    // w_qkv^T bf16 [6144][2048]
  __bf16* qbuf  = (__bf16*)(ws + 58720256);    // [B*H][T][hd]
  __bf16* kbuf  = (__bf16*)(ws + 92274688);
  __bf16* vbuf  = (__bf16*)(ws + 125829120);   // V, later attn out
  __bf16* woutT = (__bf16*)(ws + 159383552);   // w_out^T bf16 [2048][2048]

  cvt_f32_bf16<<<8192, 256, 0, stream>>>(x, xb);
  transpose_w<<<dim3(192, 64), 256, 0, stream>>>(w_qkv, wqkvT, 2048, 6144);
  transpose_w<<<dim3(64, 64), 256, 0, stream>>>(w_out, woutT, 2048, 2048);
  gemm256<0><<<dim3(24, 32), 512, 0, stream>>>(xb, wqkvT, b_qkv, 2048, 6144,
                                               qbuf, kbuf, vbuf, nullptr);
  transpose_v<<<dim3(32, 2, 64), 256, 0, stream>>>(vbuf, xb);   // xb := V^T
  attn_fwd<<<dim3(16, 64), 256, 0, stream>>>(qbuf, kbuf, xb, vbuf);  // vbuf := attn out
  gemm256<1><<<dim3(8, 32), 512, 0, stream>>>(vbuf, woutT, b_out, 2048, 2048,
                                              nullptr, nullptr, nullptr, out);
}

// Round 5
// 470.111 us; speedup vs baseline: 1.8771x; 1.1912x over previous
//
#include <hip/hip_runtime.h>
#include <hip/hip_bf16.h>

#define DEVFN static __device__ __forceinline__

typedef __attribute__((ext_vector_type(8))) __bf16 bf16x8;
typedef __attribute__((ext_vector_type(4))) float f32x4;

#define MFMA16(a, b, c) __builtin_amdgcn_mfma_f32_16x16x32_bf16(a, b, c, 0, 0, 0)

// async global->LDS, 16B per lane; dest is wave-uniform base + lane*16
DEVFN void gload16(const void* g, void* l) {
  __builtin_amdgcn_global_load_lds((const __attribute__((address_space(1))) void*)g,
                                   (__attribute__((address_space(3))) void*)l, 16, 0, 0);
}

DEVFN void vwait8() { asm volatile("s_waitcnt vmcnt(8)" ::: "memory"); __builtin_amdgcn_sched_barrier(0); }
DEVFN void vwait4() { asm volatile("s_waitcnt vmcnt(4)" ::: "memory"); __builtin_amdgcn_sched_barrier(0); }
DEVFN void vwait0() { asm volatile("s_waitcnt vmcnt(0)" ::: "memory"); __builtin_amdgcn_sched_barrier(0); }
DEVFN void lgk0()   { asm volatile("s_waitcnt lgkmcnt(0)" ::: "memory"); __builtin_amdgcn_sched_barrier(0); }
DEVFN void bar()    { __builtin_amdgcn_s_barrier(); }
// barrier + scheduling fence: nothing (esp. ds_read) may hoist above it
DEVFN void barsched() { __builtin_amdgcn_s_barrier(); __builtin_amdgcn_sched_barrier(0); }

// ---------------- f32 -> bf16 convert (vectorized) ----------------
__global__ __launch_bounds__(256) void cvt_f32_bf16(const float* __restrict__ in,
                                                    __bf16* __restrict__ out) {
  size_t i = ((size_t)blockIdx.x * 256 + threadIdx.x) * 8;
  f32x4 a = *(const f32x4*)(in + i);
  f32x4 b = *(const f32x4*)(in + i + 4);
  bf16x8 u;
  u[0] = (__bf16)a[0]; u[1] = (__bf16)a[1]; u[2] = (__bf16)a[2]; u[3] = (__bf16)a[3];
  u[4] = (__bf16)b[0]; u[5] = (__bf16)b[1]; u[6] = (__bf16)b[2]; u[7] = (__bf16)b[3];
  *(bf16x8*)(out + i) = u;
}

// ---------------- transpose f32 [K][N] -> bf16 [N][K] ----------------
__global__ __launch_bounds__(256) void transpose_w(const float* __restrict__ in,
                                                   __bf16* __restrict__ out,
                                                   int K, int N) {
  __shared__ float tile[32][33];
  const int t = threadIdx.x, tx = t & 31, ty = t >> 5;
  const int n0 = blockIdx.x * 32, k0 = blockIdx.y * 32;
#pragma unroll
  for (int r = 0; r < 4; r++)
    tile[ty + r * 8][tx] = in[(size_t)(k0 + ty + r * 8) * N + n0 + tx];
  __syncthreads();
#pragma unroll
  for (int r = 0; r < 4; r++)
    out[(size_t)(n0 + ty + r * 8) * K + k0 + tx] = (__bf16)tile[tx][ty + r * 8];
}

// ---------------- transpose bf16 [bh][T][128] -> [bh][128][T] ----------------
__global__ __launch_bounds__(256) void transpose_v(const __bf16* __restrict__ in,
                                                   __bf16* __restrict__ out) {
  __shared__ __bf16 tile[64][72];
  const int bh = blockIdx.z;
  const int t0 = blockIdx.x * 64, d0 = blockIdx.y * 64;
  const int tid = threadIdx.x;
  const int r = tid >> 3, c8 = (tid & 7) * 8;
  const __bf16* ip = in + (size_t)bh * 2048 * 128;
#pragma unroll
  for (int i = 0; i < 2; i++)
    *(bf16x8*)&tile[i * 32 + r][c8] =
        *(const bf16x8*)(ip + (size_t)(t0 + i * 32 + r) * 128 + d0 + c8);
  __syncthreads();
  __bf16* op = out + (size_t)bh * 2048 * 128;
#pragma unroll
  for (int i = 0; i < 2; i++) {
    const int dd = i * 32 + r;
    bf16x8 v;
#pragma unroll
    for (int j = 0; j < 8; j++) v[j] = tile[c8 + j][dd];
    *(bf16x8*)(op + (size_t)(d0 + dd) * 2048 + t0 + c8) = v;
  }
}

// ================= 256x256 8-phase bf16 GEMM (m201 template) =================
#define QK_SCALE 0.12751745f  // (1/sqrt(128)) * log2(e)

DEVFN void stage_tile(const __bf16* gx, size_t Kst, int t, __bf16* ldst,
                      int rr, int gsw, int w) {
#pragma unroll
  for (int j = 0; j < 4; j++)
    gload16(gx + (size_t)(j * 64 + rr) * Kst + (size_t)t * 64 + gsw,
            ldst + j * 4096 + w * 512);
}

DEVFN void tile_step(__bf16* la, __bf16* lb, f32x4 (&acc)[8][4],
                     const __bf16* ga, const __bf16* gb, size_t Kst, int t, int NT,
                     int rr, int gsw, int w, int wr, int wc, int lg, int li) {
  bf16x8 a[4][2], bl[2][2], br[2][2];
  const int sa = li & 7;
  const int arow = wr * 128 + li;
  const int brow = wc * 64 + li;

#pragma unroll
  for (int mi = 0; mi < 4; mi++)
#pragma unroll
    for (int ks = 0; ks < 2; ks++)
      a[mi][ks] = *(const bf16x8*)&la[(arow + mi * 16) * 64 + (((ks * 4 + lg) ^ sa) * 8)];
#pragma unroll
  for (int ni = 0; ni < 2; ni++)
#pragma unroll
    for (int ks = 0; ks < 2; ks++)
      bl[ni][ks] = *(const bf16x8*)&lb[(brow + ni * 16) * 64 + (((ks * 4 + lg) ^ sa) * 8)];
  bar();
  lgk0();
  __builtin_amdgcn_s_setprio(1);
#pragma unroll
  for (int mi = 0; mi < 4; mi++)
#pragma unroll
    for (int ni = 0; ni < 2; ni++)
#pragma unroll
      for (int ks = 0; ks < 2; ks++)
        acc[mi][ni] = MFMA16(a[mi][ks], bl[ni][ks], acc[mi][ni]);
  __builtin_amdgcn_s_setprio(0);
  bar();

#pragma unroll
  for (int ni = 0; ni < 2; ni++)
#pragma unroll
    for (int ks = 0; ks < 2; ks++)
      br[ni][ks] = *(const bf16x8*)&lb[(brow + (ni + 2) * 16) * 64 + (((ks * 4 + lg) ^ sa) * 8)];
  bar();
  lgk0();
  __builtin_amdgcn_s_setprio(1);
#pragma unroll
  for (int mi = 0; mi < 4; mi++)
#pragma unroll
    for (int ni = 0; ni < 2; ni++)
#pragma unroll
      for (int ks = 0; ks < 2; ks++)
        acc[mi][ni + 2] = MFMA16(a[mi][ks], br[ni][ks], acc[mi][ni + 2]);
  __builtin_amdgcn_s_setprio(0);
  bar();

#pragma unroll
  for (int mi = 0; mi < 4; mi++)
#pragma unroll
    for (int ks = 0; ks < 2; ks++)
      a[mi][ks] = *(const bf16x8*)&la[(arow + (mi + 4) * 16) * 64 + (((ks * 4 + lg) ^ sa) * 8)];
  bar();
  lgk0();
  __builtin_amdgcn_s_setprio(1);
#pragma unroll
  for (int mi = 0; mi < 4; mi++)
#pragma unroll
    for (int ni = 0; ni < 2; ni++)
#pragma unroll
      for (int ks = 0; ks < 2; ks++)
        acc[mi + 4][ni] = MFMA16(a[mi][ks], bl[ni][ks], acc[mi + 4][ni]);
  __builtin_amdgcn_s_setprio(0);
  bar();

  if (t + 2 < NT) {
    stage_tile(ga, Kst, t + 2, la, rr, gsw, w);
    stage_tile(gb, Kst, t + 2, lb, rr, gsw, w);
  }
  __builtin_amdgcn_s_setprio(1);
#pragma unroll
  for (int mi = 0; mi < 4; mi++)
#pragma unroll
    for (int ni = 0; ni < 2; ni++)
#pragma unroll
      for (int ks = 0; ks < 2; ks++)
        acc[mi + 4][ni + 2] = MFMA16(a[mi][ks], br[ni][ks], acc[mi + 4][ni + 2]);
  __builtin_amdgcn_s_setprio(0);

  if (t + 2 < NT) vwait8(); else vwait0();
  bar();
}

template <int MODE>
__global__ __launch_bounds__(512, 2) void gemm256(
    const __bf16* __restrict__ A, const __bf16* __restrict__ Bt,
    const float* __restrict__ bias, int K, int Ncols,
    __bf16* __restrict__ qo, __bf16* __restrict__ ko, __bf16* __restrict__ vo,
    float* __restrict__ outf) {
  __shared__ __align__(16) __bf16 lds[65536];
  const int tid = threadIdx.x;
  const int w = tid >> 6, lane = tid & 63;
  const int wr = w >> 2, wc = w & 3;
  const int lg = lane >> 4, li = lane & 15;
  const size_t m0 = (size_t)blockIdx.y * 256;
  const size_t n0 = (size_t)blockIdx.x * 256;
  const int rr = tid >> 3;
  const int gsw = ((tid & 7) ^ (rr & 7)) * 8;
  const __bf16* ga = A + m0 * K;
  const __bf16* gb = Bt + n0 * K;
  const int NT = K >> 6;

  __bf16* la0 = lds;
  __bf16* la1 = lds + 16384;
  __bf16* lb0 = lds + 32768;
  __bf16* lb1 = lds + 49152;

  f32x4 acc[8][4] = {};

  stage_tile(ga, K, 0, la0, rr, gsw, w);
  stage_tile(gb, K, 0, lb0, rr, gsw, w);
  stage_tile(ga, K, 1, la1, rr, gsw, w);
  stage_tile(gb, K, 1, lb1, rr, gsw, w);
  vwait8();
  bar();

  for (int t = 0; t < NT; t += 2) {
    tile_step(la0, lb0, acc, ga, gb, K, t,     NT, rr, gsw, w, wr, wc, lg, li);
    tile_step(la1, lb1, acc, ga, gb, K, t + 1, NT, rr, gsw, w, wr, wc, lg, li);
  }

  if (MODE == 0) {
    const int which = (int)(n0 >> 11);
    const int b = (int)(m0 >> 11);
    __bf16* outp = (which == 0) ? qo : ((which == 1) ? ko : vo);
    const float scale = (which == 0) ? QK_SCALE : 1.0f;
#pragma unroll
    for (int ni = 0; ni < 4; ni++) {
      const int ncol = (int)n0 + wc * 64 + ni * 16 + li;
      const float bv = bias[ncol];
      const int h = (ncol & 2047) >> 7;
      const int d = ncol & 127;
      const size_t base = (size_t)(b * 16 + h) * (2048 * 128) + d;
#pragma unroll
      for (int mi = 0; mi < 8; mi++)
#pragma unroll
        for (int r = 0; r < 4; r++) {
          const int tt = ((int)m0 + wr * 128 + mi * 16 + lg * 4 + r) & 2047;
          outp[base + (size_t)tt * 128] = (__bf16)((acc[mi][ni][r] + bv) * scale);
        }
    }
  } else {
#pragma unroll
    for (int ni = 0; ni < 4; ni++) {
      const int ncol = (int)n0 + wc * 64 + ni * 16 + li;
      const float bv = bias[ncol];
#pragma unroll
      for (int mi = 0; mi < 8; mi++)
#pragma unroll
        for (int r = 0; r < 4; r++) {
          const size_t mrow = m0 + wr * 128 + mi * 16 + lg * 4 + r;
          outf[mrow * Ncols + ncol] = acc[mi][ni][r] + bv;
        }
    }
  }
}

// ---------------- causal flash attention, pipelined staging ----------------
// grid (8, 64): block bx handles q-tiles (15-bx) then (bx) -> 34 tiles/block.
// Per tile: [vmcnt(4); bar] K ready -> QK -> bar -> issue K(t+1) -> softmax ->
// [vmcnt(4); bar] V ready -> PV -> bar -> issue V(t+1). Prefetch stays in
// flight across barriers (counted vmcnt, never 0 mid-loop).
DEVFN void attn_stageK(const __bf16* const (&ksrc)[4], int k0, __bf16* Kl, int w) {
#pragma unroll
  for (int i = 0; i < 4; i++)
    gload16(ksrc[i] + (size_t)k0 * 128, Kl + i * 2048 + w * 512);
}
DEVFN void attn_stageV(const __bf16* const (&vsrc)[4], int k0, __bf16* Vl, int w) {
#pragma unroll
  for (int i = 0; i < 4; i++)
    gload16(vsrc[i] + k0, Vl + i * 2048 + w * 512);
}

template <bool DIAG>
DEVFN void attn_tile(int kt, int n, int q0, int w, int lg, int li,
                     const __bf16* const (&ksrc)[4], const __bf16* const (&vsrc)[4],
                     __bf16* Kl, __bf16* Vl, __bf16* Pl,
                     const bf16x8 (&qf)[2][4], f32x4 (&o)[2][8],
                     float (&mrow)[2][4], float (&lrow)[2][4]) {
  const int k0 = kt * 64;
  const bool more = (kt + 1 < n);

  vwait4();      // K(kt) landed (V(kt) still in flight)
  barsched();    // ...in every wave

  // S = Q K^T
  f32x4 s[2][4] = {};
#pragma unroll
  for (int kk = 0; kk < 4; kk++) {
    bf16x8 bk[4];
#pragma unroll
    for (int ni = 0; ni < 4; ni++) {
      const int key = ni * 16 + li;
      bk[ni] = *(const bf16x8*)&Kl[key * 128 + ((kk * 32 + lg * 8) ^ ((key & 7) << 3))];
    }
#pragma unroll
    for (int mi = 0; mi < 2; mi++)
#pragma unroll
      for (int ni = 0; ni < 4; ni++)
        s[mi][ni] = MFMA16(qf[mi][kk], bk[ni], s[mi][ni]);
  }
  barsched();    // all waves done reading Kl
  if (more) attn_stageK(ksrc, k0 + 64, Kl, w);   // prefetch under softmax+PV

  // online softmax (base-2) with defer-max; P rows are per-wave private
#pragma unroll
  for (int mi = 0; mi < 2; mi++) {
#pragma unroll
    for (int r = 0; r < 4; r++) {
      const int prow = w * 32 + mi * 16 + lg * 4 + r;
      float vals[4];
#pragma unroll
      for (int ni = 0; ni < 4; ni++) {
        float x = s[mi][ni][r];
        if (DIAG) {
          if ((k0 + ni * 16 + li) > (q0 + prow)) x = -1e30f;
        }
        vals[ni] = x;
      }
      float vmax = fmaxf(fmaxf(vals[0], vals[1]), fmaxf(vals[2], vals[3]));
      vmax = fmaxf(vmax, __shfl_xor(vmax, 1));
      vmax = fmaxf(vmax, __shfl_xor(vmax, 2));
      vmax = fmaxf(vmax, __shfl_xor(vmax, 4));
      vmax = fmaxf(vmax, __shfl_xor(vmax, 8));
      float mref = mrow[mi][r];
      if (vmax - mref > 8.0f) {
        const float sc = __builtin_amdgcn_exp2f(mref - vmax);
        lrow[mi][r] *= sc;
#pragma unroll
        for (int nd = 0; nd < 8; nd++) o[mi][nd][r] *= sc;
        mrow[mi][r] = vmax;
        mref = vmax;
      }
      float ps = 0.f;
#pragma unroll
      for (int ni = 0; ni < 4; ni++) {
        const float p = __builtin_amdgcn_exp2f(vals[ni] - mref);
        ps += p;
        Pl[prow * 72 + ni * 16 + li] = (__bf16)p;
      }
      ps += __shfl_xor(ps, 1);
      ps += __shfl_xor(ps, 2);
      ps += __shfl_xor(ps, 4);
      ps += __shfl_xor(ps, 8);
      lrow[mi][r] += ps;
    }
  }

  if (more) vwait4(); else vwait0();   // V(kt) landed (K(kt+1) may remain)
  barsched();

  // O += P V
#pragma unroll
  for (int kk = 0; kk < 2; kk++) {
    bf16x8 pf[2];
#pragma unroll
    for (int mi = 0; mi < 2; mi++)
      pf[mi] = *(const bf16x8*)&Pl[(w * 32 + mi * 16 + li) * 72 + kk * 32 + lg * 8];
#pragma unroll
    for (int nd = 0; nd < 8; nd++) {
      const int d = nd * 16 + li;
      const int swd = ((d ^ (d >> 3)) & 7) << 3;
      bf16x8 vf = *(const bf16x8*)&Vl[d * 64 + ((kk * 32 + lg * 8) ^ swd)];
#pragma unroll
      for (int mi = 0; mi < 2; mi++)
        o[mi][nd] = MFMA16(pf[mi], vf, o[mi][nd]);
    }
  }
  barsched();    // all waves done reading Vl
  if (more) attn_stageV(vsrc, k0 + 64, Vl, w);   // prefetch under next QK+softmax
}

DEVFN void attn_run(int qt, int bh, int w, int lg, int li,
                    const __bf16* qp, __bf16* ob,
                    const __bf16* const (&ksrc)[4], const __bf16* const (&vsrc)[4],
                    __bf16* Kl, __bf16* Vl, __bf16* Pl) {
  const int q0 = qt * 128;
  // Q fragments (VMEM loads; drained by the first tile's vmcnt waits)
  bf16x8 qf[2][4];
#pragma unroll
  for (int mi = 0; mi < 2; mi++)
#pragma unroll
    for (int kk = 0; kk < 4; kk++)
      qf[mi][kk] = *(const bf16x8*)(qp + (size_t)(q0 + w * 32 + mi * 16 + li) * 128 + kk * 32 + lg * 8);

  f32x4 o[2][8] = {};
  float mrow[2][4], lrow[2][4];
#pragma unroll
  for (int mi = 0; mi < 2; mi++)
#pragma unroll
    for (int r = 0; r < 4; r++) { mrow[mi][r] = -1e30f; lrow[mi][r] = 0.f; }

  const int n = 2 * qt + 2;
  attn_stageK(ksrc, 0, Kl, w);
  attn_stageV(vsrc, 0, Vl, w);

  for (int kt = 0; kt < n - 2; kt++)
    attn_tile<false>(kt, n, q0, w, lg, li, ksrc, vsrc, Kl, Vl, Pl, qf, o, mrow, lrow);
  attn_tile<true>(n - 2, n, q0, w, lg, li, ksrc, vsrc, Kl, Vl, Pl, qf, o, mrow, lrow);
  attn_tile<true>(n - 1, n, q0, w, lg, li, ksrc, vsrc, Kl, Vl, Pl, qf, o, mrow, lrow);

  const int b = bh >> 4, h = bh & 15;
#pragma unroll
  for (int mi = 0; mi < 2; mi++) {
    float inv[4];
#pragma unroll
    for (int r = 0; r < 4; r++) inv[r] = 1.0f / lrow[mi][r];
#pragma unroll
    for (int nd = 0; nd < 8; nd++)
#pragma unroll
      for (int r = 0; r < 4; r++)
        ob[(size_t)(b * 2048 + q0 + w * 32 + mi * 16 + lg * 4 + r) * 2048 + h * 128 + nd * 16 + li]
            = (__bf16)(o[mi][nd][r] * inv[r]);
  }
}

__global__ __launch_bounds__(256, 2) void attn_fwd(
    const __bf16* __restrict__ qb, const __bf16* __restrict__ kb,
    const __bf16* __restrict__ vtb, __bf16* __restrict__ ob) {
  __shared__ __align__(16) __bf16 Kl[64 * 128];
  __shared__ __align__(16) __bf16 Vl[128 * 64];
  __shared__ __align__(16) __bf16 Pl[128 * 72];
  const int bx = blockIdx.x;      // 0..7
  const int bh = blockIdx.y;
  const int tid = threadIdx.x;
  const int w = tid >> 6, l = tid & 63;
  const int lg = l >> 4, li = l & 15;
  const __bf16* qp = qb + (size_t)bh * (2048 * 128);
  const __bf16* kp = kb + (size_t)bh * (2048 * 128);
  const __bf16* vtp = vtb + (size_t)bh * (2048 * 128);

  const __bf16* ksrc[4];
  const __bf16* vsrc[4];
#pragma unroll
  for (int i = 0; i < 4; i++) {
    const int key = i * 16 + w * 4 + lg;
    ksrc[i] = kp + (size_t)key * 128 + 8 * (li ^ (key & 7));
    const int d = i * 32 + (tid >> 3);
    const int g = (tid & 7) ^ ((d ^ (d >> 3)) & 7);
    vsrc[i] = vtp + (size_t)d * 2048 + g * 8;
  }

  // large q-tile first, then the small one: 34 tiles total per block
  attn_run(15 - bx, bh, w, lg, li, qp, ob, ksrc, vsrc, Kl, Vl, Pl);
  attn_run(bx,      bh, w, lg, li, qp, ob, ksrc, vsrc, Kl, Vl, Pl);
}

extern "C" void kernel_launch(void* const* d_in, const int* in_sizes, int n_in,
                              void* d_out, int out_size, void* d_ws, size_t ws_size,
                              hipStream_t stream) {
  (void)in_sizes; (void)n_in; (void)out_size; (void)ws_size;
  const float* x     = (const float*)d_in[0];
  const float* w_qkv = (const float*)d_in[1];
  const float* b_qkv = (const float*)d_in[2];
  const float* w_out = (const float*)d_in[3];
  const float* b_out = (const float*)d_in[4];
  float* out = (float*)d_out;
  char* ws = (char*)d_ws;

  __bf16* xb    = (__bf16*)(ws + 0);           // x-bf16, later V^T
  __bf16* wqkvT = (__bf16*)(ws + 33554432);    // w_qkv^T bf16 [6144][2048]
  __bf16* qbuf  = (__bf16*)(ws + 58720256);    // [B*H][T][hd]
  __bf16* kbuf  = (__bf16*)(ws + 92274688);
  __bf16* vbuf  = (__bf16*)(ws + 125829120);   // V, later attn out
  __bf16* woutT = (__bf16*)(ws + 159383552);   // w_out^T bf16 [2048][2048]

  cvt_f32_bf16<<<8192, 256, 0, stream>>>(x, xb);
  transpose_w<<<dim3(192, 64), 256, 0, stream>>>(w_qkv, wqkvT, 2048, 6144);
  transpose_w<<<dim3(64, 64), 256, 0, stream>>>(w_out, woutT, 2048, 2048);
  gemm256<0><<<dim3(24, 32), 512, 0, stream>>>(xb, wqkvT, b_qkv, 2048, 6144,
                                               qbuf, kbuf, vbuf, nullptr);
  transpose_v<<<dim3(32, 2, 64), 256, 0, stream>>>(vbuf, xb);   // xb := V^T
  attn_fwd<<<dim3(8, 64), 256, 0, stream>>>(qbuf, kbuf, xb, vbuf);  // vbuf := attn out
  gemm256<1><<<dim3(8, 32), 512, 0, stream>>>(vbuf, woutT, b_out, 2048, 2048,
                                              nullptr, nullptr, nullptr, out);
}

// Round 6
// 452.505 us; speedup vs baseline: 1.9501x; 1.0389x over previous
//
#include <hip/hip_runtime.h>
#include <hip/hip_bf16.h>

#define DEVFN static __device__ __forceinline__

typedef __attribute__((ext_vector_type(8))) __bf16 bf16x8;
typedef __attribute__((ext_vector_type(4))) float f32x4;

#define MFMA16(a, b, c) __builtin_amdgcn_mfma_f32_16x16x32_bf16(a, b, c, 0, 0, 0)

// async global->LDS, 16B per lane; dest is wave-uniform base + lane*16
DEVFN void gload16(const void* g, void* l) {
  __builtin_amdgcn_global_load_lds((const __attribute__((address_space(1))) void*)g,
                                   (__attribute__((address_space(3))) void*)l, 16, 0, 0);
}

DEVFN void vwait8() { asm volatile("s_waitcnt vmcnt(8)" ::: "memory"); __builtin_amdgcn_sched_barrier(0); }
DEVFN void vwait4() { asm volatile("s_waitcnt vmcnt(4)" ::: "memory"); __builtin_amdgcn_sched_barrier(0); }
DEVFN void vwait0() { asm volatile("s_waitcnt vmcnt(0)" ::: "memory"); __builtin_amdgcn_sched_barrier(0); }
DEVFN void bar()    { __builtin_amdgcn_s_barrier(); }
// barrier + scheduling fence: nothing may hoist above this point
DEVFN void barsched() { __builtin_amdgcn_s_barrier(); __builtin_amdgcn_sched_barrier(0); }

// ---------------- f32 -> bf16 convert (vectorized) ----------------
__global__ __launch_bounds__(256) void cvt_f32_bf16(const float* __restrict__ in,
                                                    __bf16* __restrict__ out) {
  size_t i = ((size_t)blockIdx.x * 256 + threadIdx.x) * 8;
  f32x4 a = *(const f32x4*)(in + i);
  f32x4 b = *(const f32x4*)(in + i + 4);
  bf16x8 u;
  u[0] = (__bf16)a[0]; u[1] = (__bf16)a[1]; u[2] = (__bf16)a[2]; u[3] = (__bf16)a[3];
  u[4] = (__bf16)b[0]; u[5] = (__bf16)b[1]; u[6] = (__bf16)b[2]; u[7] = (__bf16)b[3];
  *(bf16x8*)(out + i) = u;
}

// ---------------- transpose f32 [K][N] -> bf16 [N][K] ----------------
__global__ __launch_bounds__(256) void transpose_w(const float* __restrict__ in,
                                                   __bf16* __restrict__ out,
                                                   int K, int N) {
  __shared__ float tile[32][33];
  const int t = threadIdx.x, tx = t & 31, ty = t >> 5;
  const int n0 = blockIdx.x * 32, k0 = blockIdx.y * 32;
#pragma unroll
  for (int r = 0; r < 4; r++)
    tile[ty + r * 8][tx] = in[(size_t)(k0 + ty + r * 8) * N + n0 + tx];
  __syncthreads();
#pragma unroll
  for (int r = 0; r < 4; r++)
    out[(size_t)(n0 + ty + r * 8) * K + k0 + tx] = (__bf16)tile[tx][ty + r * 8];
}

// ---------------- transpose bf16 [bh][T][128] -> [bh][128][T] ----------------
__global__ __launch_bounds__(256) void transpose_v(const __bf16* __restrict__ in,
                                                   __bf16* __restrict__ out) {
  __shared__ __bf16 tile[64][72];
  const int bh = blockIdx.z;
  const int t0 = blockIdx.x * 64, d0 = blockIdx.y * 64;
  const int tid = threadIdx.x;
  const int r = tid >> 3, c8 = (tid & 7) * 8;
  const __bf16* ip = in + (size_t)bh * 2048 * 128;
#pragma unroll
  for (int i = 0; i < 2; i++)
    *(bf16x8*)&tile[i * 32 + r][c8] =
        *(const bf16x8*)(ip + (size_t)(t0 + i * 32 + r) * 128 + d0 + c8);
  __syncthreads();
  __bf16* op = out + (size_t)bh * 2048 * 128;
#pragma unroll
  for (int i = 0; i < 2; i++) {
    const int dd = i * 32 + r;
    bf16x8 v;
#pragma unroll
    for (int j = 0; j < 8; j++) v[j] = tile[c8 + j][dd];
    *(bf16x8*)(op + (size_t)(d0 + dd) * 2048 + t0 + c8) = v;
  }
}

// ================= 256x256 8-phase bf16 GEMM (m201 template) =================
#define QK_SCALE 0.12751745f  // (1/sqrt(128)) * log2(e)

DEVFN void stage_tile(const __bf16* gx, size_t Kst, int t, __bf16* ldst,
                      int rr, int gsw, int w) {
#pragma unroll
  for (int j = 0; j < 4; j++)
    gload16(gx + (size_t)(j * 64 + rr) * Kst + (size_t)t * 64 + gsw,
            ldst + j * 4096 + w * 512);
}

// Per K-tile: 4 phases x 16 MFMA. Stage of tile t+2 is spread:
//   B-stage at phase-3 open (B fully read by end of phase 2),
//   A-stage at phase-4 open (A fully read by end of phase 3).
// No explicit lgkmcnt: ds_reads are compiler-visible -> fine-grained waits.
DEVFN void tile_step(__bf16* la, __bf16* lb, f32x4 (&acc)[8][4],
                     const __bf16* ga, const __bf16* gb, size_t Kst, int t, int NT,
                     int rr, int gsw, int w, int wr, int wc, int lg, int li) {
  bf16x8 a[4][2], bl[2][2], br[2][2];
  const int sa = li & 7;
  const int arow = wr * 128 + li;
  const int brow = wc * 64 + li;
  const bool pf = (t + 2 < NT);

  // ---- phase 1: read A(mi0-3) + B(ni0-1); MFMA quadrant (mi0-3 x ni0-1)
#pragma unroll
  for (int mi = 0; mi < 4; mi++)
#pragma unroll
    for (int ks = 0; ks < 2; ks++)
      a[mi][ks] = *(const bf16x8*)&la[(arow + mi * 16) * 64 + (((ks * 4 + lg) ^ sa) * 8)];
#pragma unroll
  for (int ni = 0; ni < 2; ni++)
#pragma unroll
    for (int ks = 0; ks < 2; ks++)
      bl[ni][ks] = *(const bf16x8*)&lb[(brow + ni * 16) * 64 + (((ks * 4 + lg) ^ sa) * 8)];
  bar();
  __builtin_amdgcn_s_setprio(1);
#pragma unroll
  for (int mi = 0; mi < 4; mi++)
#pragma unroll
    for (int ni = 0; ni < 2; ni++)
#pragma unroll
      for (int ks = 0; ks < 2; ks++)
        acc[mi][ni] = MFMA16(a[mi][ks], bl[ni][ks], acc[mi][ni]);
  __builtin_amdgcn_s_setprio(0);
  bar();

  // ---- phase 2: read B(ni2-3); MFMA (mi0-3 x ni2-3)
#pragma unroll
  for (int ni = 0; ni < 2; ni++)
#pragma unroll
    for (int ks = 0; ks < 2; ks++)
      br[ni][ks] = *(const bf16x8*)&lb[(brow + (ni + 2) * 16) * 64 + (((ks * 4 + lg) ^ sa) * 8)];
  bar();
  __builtin_amdgcn_s_setprio(1);
#pragma unroll
  for (int mi = 0; mi < 4; mi++)
#pragma unroll
    for (int ni = 0; ni < 2; ni++)
#pragma unroll
      for (int ks = 0; ks < 2; ks++)
        acc[mi][ni + 2] = MFMA16(a[mi][ks], br[ni][ks], acc[mi][ni + 2]);
  __builtin_amdgcn_s_setprio(0);
  barsched();   // B tile fully read by all waves past this point

  // ---- phase 3: stage B(t+2); read A(mi4-7); MFMA (mi4-7 x ni0-1)
  if (pf) stage_tile(gb, Kst, t + 2, lb, rr, gsw, w);
#pragma unroll
  for (int mi = 0; mi < 4; mi++)
#pragma unroll
    for (int ks = 0; ks < 2; ks++)
      a[mi][ks] = *(const bf16x8*)&la[(arow + (mi + 4) * 16) * 64 + (((ks * 4 + lg) ^ sa) * 8)];
  bar();
  __builtin_amdgcn_s_setprio(1);
#pragma unroll
  for (int mi = 0; mi < 4; mi++)
#pragma unroll
    for (int ni = 0; ni < 2; ni++)
#pragma unroll
      for (int ks = 0; ks < 2; ks++)
        acc[mi + 4][ni] = MFMA16(a[mi][ks], bl[ni][ks], acc[mi + 4][ni]);
  __builtin_amdgcn_s_setprio(0);
  barsched();   // A tile fully read by all waves past this point

  // ---- phase 4: stage A(t+2); MFMA (mi4-7 x ni2-3)
  if (pf) stage_tile(ga, Kst, t + 2, la, rr, gsw, w);
  __builtin_amdgcn_s_setprio(1);
#pragma unroll
  for (int mi = 0; mi < 4; mi++)
#pragma unroll
    for (int ni = 0; ni < 2; ni++)
#pragma unroll
      for (int ks = 0; ks < 2; ks++)
        acc[mi + 4][ni + 2] = MFMA16(a[mi][ks], br[ni][ks], acc[mi + 4][ni + 2]);
  __builtin_amdgcn_s_setprio(0);

  // retire tile t+1's loads; leave t+2's 8 in flight (counted vmcnt, T4)
  if (pf) vwait8(); else vwait0();
  bar();
}

template <int MODE>
__global__ __launch_bounds__(512, 2) void gemm256(
    const __bf16* __restrict__ A, const __bf16* __restrict__ Bt,
    const float* __restrict__ bias, int K, int Ncols,
    __bf16* __restrict__ qo, __bf16* __restrict__ ko, __bf16* __restrict__ vo,
    float* __restrict__ outf) {
  __shared__ __align__(16) __bf16 lds[65536];
  const int tid = threadIdx.x;
  const int w = tid >> 6, lane = tid & 63;
  const int wr = w >> 2, wc = w & 3;
  const int lg = lane >> 4, li = lane & 15;
  // XCD-aware swizzle (T1): nwg % 8 == 0 for all launches here
  const int nbx = gridDim.x;
  const int nwg = nbx * gridDim.y;
  const int orig = blockIdx.y * nbx + blockIdx.x;
  const int swz = (orig & 7) * (nwg >> 3) + (orig >> 3);
  const size_t m0 = (size_t)(swz / nbx) * 256;
  const size_t n0 = (size_t)(swz % nbx) * 256;
  const int rr = tid >> 3;
  const int gsw = ((tid & 7) ^ (rr & 7)) * 8;
  const __bf16* ga = A + m0 * K;
  const __bf16* gb = Bt + n0 * K;
  const int NT = K >> 6;

  __bf16* la0 = lds;
  __bf16* la1 = lds + 16384;
  __bf16* lb0 = lds + 32768;
  __bf16* lb1 = lds + 49152;

  f32x4 acc[8][4] = {};

  stage_tile(ga, K, 0, la0, rr, gsw, w);
  stage_tile(gb, K, 0, lb0, rr, gsw, w);
  stage_tile(ga, K, 1, la1, rr, gsw, w);
  stage_tile(gb, K, 1, lb1, rr, gsw, w);
  vwait8();
  bar();

  for (int t = 0; t < NT; t += 2) {
    tile_step(la0, lb0, acc, ga, gb, K, t,     NT, rr, gsw, w, wr, wc, lg, li);
    tile_step(la1, lb1, acc, ga, gb, K, t + 1, NT, rr, gsw, w, wr, wc, lg, li);
  }

  if (MODE == 0) {
    const int which = (int)(n0 >> 11);
    const int b = (int)(m0 >> 11);
    __bf16* outp = (which == 0) ? qo : ((which == 1) ? ko : vo);
    const float scale = (which == 0) ? QK_SCALE : 1.0f;
#pragma unroll
    for (int ni = 0; ni < 4; ni++) {
      const int ncol = (int)n0 + wc * 64 + ni * 16 + li;
      const float bv = bias[ncol];
      const int h = (ncol & 2047) >> 7;
      const int d = ncol & 127;
      const size_t base = (size_t)(b * 16 + h) * (2048 * 128) + d;
#pragma unroll
      for (int mi = 0; mi < 8; mi++)
#pragma unroll
        for (int r = 0; r < 4; r++) {
          const int tt = ((int)m0 + wr * 128 + mi * 16 + lg * 4 + r) & 2047;
          outp[base + (size_t)tt * 128] = (__bf16)((acc[mi][ni][r] + bv) * scale);
        }
    }
  } else {
#pragma unroll
    for (int ni = 0; ni < 4; ni++) {
      const int ncol = (int)n0 + wc * 64 + ni * 16 + li;
      const float bv = bias[ncol];
#pragma unroll
      for (int mi = 0; mi < 8; mi++)
#pragma unroll
        for (int r = 0; r < 4; r++) {
          const size_t mrow = m0 + wr * 128 + mi * 16 + lg * 4 + r;
          outf[mrow * Ncols + ncol] = acc[mi][ni][r] + bv;
        }
    }
  }
}

// ---------------- causal flash attention, pipelined staging ----------------
DEVFN void attn_stageK(const __bf16* const (&ksrc)[4], int k0, __bf16* Kl, int w) {
#pragma unroll
  for (int i = 0; i < 4; i++)
    gload16(ksrc[i] + (size_t)k0 * 128, Kl + i * 2048 + w * 512);
}
DEVFN void attn_stageV(const __bf16* const (&vsrc)[4], int k0, __bf16* Vl, int w) {
#pragma unroll
  for (int i = 0; i < 4; i++)
    gload16(vsrc[i] + k0, Vl + i * 2048 + w * 512);
}

template <bool DIAG>
DEVFN void attn_tile(int kt, int n, int q0, int w, int lg, int li,
                     const __bf16* const (&ksrc)[4], const __bf16* const (&vsrc)[4],
                     __bf16* Kl, __bf16* Vl, __bf16* Pl,
                     const bf16x8 (&qf)[2][4], f32x4 (&o)[2][8],
                     float (&mrow)[2][4], float (&lrow)[2][4]) {
  const int k0 = kt * 64;
  const bool more = (kt + 1 < n);

  vwait4();      // K(kt) landed (V(kt) still in flight)
  barsched();

  // S = Q K^T
  f32x4 s[2][4] = {};
#pragma unroll
  for (int kk = 0; kk < 4; kk++) {
    bf16x8 bk[4];
#pragma unroll
    for (int ni = 0; ni < 4; ni++) {
      const int key = ni * 16 + li;
      bk[ni] = *(const bf16x8*)&Kl[key * 128 + ((kk * 32 + lg * 8) ^ ((key & 7) << 3))];
    }
#pragma unroll
    for (int mi = 0; mi < 2; mi++)
#pragma unroll
      for (int ni = 0; ni < 4; ni++)
        s[mi][ni] = MFMA16(qf[mi][kk], bk[ni], s[mi][ni]);
  }
  barsched();    // all waves done reading Kl
  if (more) attn_stageK(ksrc, k0 + 64, Kl, w);

  // online softmax (base-2) with defer-max
#pragma unroll
  for (int mi = 0; mi < 2; mi++) {
#pragma unroll
    for (int r = 0; r < 4; r++) {
      const int prow = w * 32 + mi * 16 + lg * 4 + r;
      float vals[4];
#pragma unroll
      for (int ni = 0; ni < 4; ni++) {
        float x = s[mi][ni][r];
        if (DIAG) {
          if ((k0 + ni * 16 + li) > (q0 + prow)) x = -1e30f;
        }
        vals[ni] = x;
      }
      float vmax = fmaxf(fmaxf(vals[0], vals[1]), fmaxf(vals[2], vals[3]));
      vmax = fmaxf(vmax, __shfl_xor(vmax, 1));
      vmax = fmaxf(vmax, __shfl_xor(vmax, 2));
      vmax = fmaxf(vmax, __shfl_xor(vmax, 4));
      vmax = fmaxf(vmax, __shfl_xor(vmax, 8));
      float mref = mrow[mi][r];
      if (vmax - mref > 8.0f) {
        const float sc = __builtin_amdgcn_exp2f(mref - vmax);
        lrow[mi][r] *= sc;
#pragma unroll
        for (int nd = 0; nd < 8; nd++) o[mi][nd][r] *= sc;
        mrow[mi][r] = vmax;
        mref = vmax;
      }
      float ps = 0.f;
#pragma unroll
      for (int ni = 0; ni < 4; ni++) {
        const float p = __builtin_amdgcn_exp2f(vals[ni] - mref);
        ps += p;
        Pl[prow * 72 + ni * 16 + li] = (__bf16)p;
      }
      ps += __shfl_xor(ps, 1);
      ps += __shfl_xor(ps, 2);
      ps += __shfl_xor(ps, 4);
      ps += __shfl_xor(ps, 8);
      lrow[mi][r] += ps;
    }
  }

  if (more) vwait4(); else vwait0();   // V(kt) landed (K(kt+1) may remain)
  barsched();

  // O += P V
#pragma unroll
  for (int kk = 0; kk < 2; kk++) {
    bf16x8 pf[2];
#pragma unroll
    for (int mi = 0; mi < 2; mi++)
      pf[mi] = *(const bf16x8*)&Pl[(w * 32 + mi * 16 + li) * 72 + kk * 32 + lg * 8];
#pragma unroll
    for (int nd = 0; nd < 8; nd++) {
      const int d = nd * 16 + li;
      const int swd = ((d ^ (d >> 3)) & 7) << 3;
      bf16x8 vf = *(const bf16x8*)&Vl[d * 64 + ((kk * 32 + lg * 8) ^ swd)];
#pragma unroll
      for (int mi = 0; mi < 2; mi++)
        o[mi][nd] = MFMA16(pf[mi], vf, o[mi][nd]);
    }
  }
  barsched();    // all waves done reading Vl
  if (more) attn_stageV(vsrc, k0 + 64, Vl, w);
}

DEVFN void attn_run(int qt, int bh, int w, int lg, int li,
                    const __bf16* qp, __bf16* ob,
                    const __bf16* const (&ksrc)[4], const __bf16* const (&vsrc)[4],
                    __bf16* Kl, __bf16* Vl, __bf16* Pl) {
  const int q0 = qt * 128;
  bf16x8 qf[2][4];
#pragma unroll
  for (int mi = 0; mi < 2; mi++)
#pragma unroll
    for (int kk = 0; kk < 4; kk++)
      qf[mi][kk] = *(const bf16x8*)(qp + (size_t)(q0 + w * 32 + mi * 16 + li) * 128 + kk * 32 + lg * 8);

  f32x4 o[2][8] = {};
  float mrow[2][4], lrow[2][4];
#pragma unroll
  for (int mi = 0; mi < 2; mi++)
#pragma unroll
    for (int r = 0; r < 4; r++) { mrow[mi][r] = -1e30f; lrow[mi][r] = 0.f; }

  const int n = 2 * qt + 2;
  attn_stageK(ksrc, 0, Kl, w);
  attn_stageV(vsrc, 0, Vl, w);

  for (int kt = 0; kt < n - 2; kt++)
    attn_tile<false>(kt, n, q0, w, lg, li, ksrc, vsrc, Kl, Vl, Pl, qf, o, mrow, lrow);
  attn_tile<true>(n - 2, n, q0, w, lg, li, ksrc, vsrc, Kl, Vl, Pl, qf, o, mrow, lrow);
  attn_tile<true>(n - 1, n, q0, w, lg, li, ksrc, vsrc, Kl, Vl, Pl, qf, o, mrow, lrow);

  const int b = bh >> 4, h = bh & 15;
#pragma unroll
  for (int mi = 0; mi < 2; mi++) {
    float inv[4];
#pragma unroll
    for (int r = 0; r < 4; r++) inv[r] = 1.0f / lrow[mi][r];
#pragma unroll
    for (int nd = 0; nd < 8; nd++)
#pragma unroll
      for (int r = 0; r < 4; r++)
        ob[(size_t)(b * 2048 + q0 + w * 32 + mi * 16 + lg * 4 + r) * 2048 + h * 128 + nd * 16 + li]
            = (__bf16)(o[mi][nd][r] * inv[r]);
  }
}

__global__ __launch_bounds__(256, 2) void attn_fwd(
    const __bf16* __restrict__ qb, const __bf16* __restrict__ kb,
    const __bf16* __restrict__ vtb, __bf16* __restrict__ ob) {
  __shared__ __align__(16) __bf16 Kl[64 * 128];
  __shared__ __align__(16) __bf16 Vl[128 * 64];
  __shared__ __align__(16) __bf16 Pl[128 * 72];
  // XCD swizzle: all 8 q-blocks of a bh land on one XCD (K/V L2 locality)
  const int orig = (int)blockIdx.y * 8 + (int)blockIdx.x;
  const int swz = (orig & 7) * 64 + (orig >> 3);
  const int bx = swz & 7;
  const int bh = swz >> 3;
  const int tid = threadIdx.x;
  const int w = tid >> 6, l = tid & 63;
  const int lg = l >> 4, li = l & 15;
  const __bf16* qp = qb + (size_t)bh * (2048 * 128);
  const __bf16* kp = kb + (size_t)bh * (2048 * 128);
  const __bf16* vtp = vtb + (size_t)bh * (2048 * 128);

  const __bf16* ksrc[4];
  const __bf16* vsrc[4];
#pragma unroll
  for (int i = 0; i < 4; i++) {
    const int key = i * 16 + w * 4 + lg;
    ksrc[i] = kp + (size_t)key * 128 + 8 * (li ^ (key & 7));
    const int d = i * 32 + (tid >> 3);
    const int g = (tid & 7) ^ ((d ^ (d >> 3)) & 7);
    vsrc[i] = vtp + (size_t)d * 2048 + g * 8;
  }

  // large q-tile first, then the small one: 34 tiles total per block
  attn_run(15 - bx, bh, w, lg, li, qp, ob, ksrc, vsrc, Kl, Vl, Pl);
  attn_run(bx,      bh, w, lg, li, qp, ob, ksrc, vsrc, Kl, Vl, Pl);
}

extern "C" void kernel_launch(void* const* d_in, const int* in_sizes, int n_in,
                              void* d_out, int out_size, void* d_ws, size_t ws_size,
                              hipStream_t stream) {
  (void)in_sizes; (void)n_in; (void)out_size; (void)ws_size;
  const float* x     = (const float*)d_in[0];
  const float* w_qkv = (const float*)d_in[1];
  const float* b_qkv = (const float*)d_in[2];
  const float* w_out = (const float*)d_in[3];
  const float* b_out = (const float*)d_in[4];
  float* out = (float*)d_out;
  char* ws = (char*)d_ws;

  __bf16* xb    = (__bf16*)(ws + 0);           // x-bf16, later V^T
  __bf16* wqkvT = (__bf16*)(ws + 33554432);    // w_qkv^T bf16 [6144][2048]
  __bf16* qbuf  = (__bf16*)(ws + 58720256);    // [B*H][T][hd]
  __bf16* kbuf  = (__bf16*)(ws + 92274688);
  __bf16* vbuf  = (__bf16*)(ws + 125829120);   // V, later attn out
  __bf16* woutT = (__bf16*)(ws + 159383552);   // w_out^T bf16 [2048][2048]

  cvt_f32_bf16<<<8192, 256, 0, stream>>>(x, xb);
  transpose_w<<<dim3(192, 64), 256, 0, stream>>>(w_qkv, wqkvT, 2048, 6144);
  transpose_w<<<dim3(64, 64), 256, 0, stream>>>(w_out, woutT, 2048, 2048);
  gemm256<0><<<dim3(24, 32), 512, 0, stream>>>(xb, wqkvT, b_qkv, 2048, 6144,
                                               qbuf, kbuf, vbuf, nullptr);
  transpose_v<<<dim3(32, 2, 64), 256, 0, stream>>>(vbuf, xb);   // xb := V^T
  attn_fwd<<<dim3(8, 64), 256, 0, stream>>>(qbuf, kbuf, xb, vbuf);  // vbuf := attn out
  gemm256<1><<<dim3(8, 32), 512, 0, stream>>>(vbuf, woutT, b_out, 2048, 2048,
                                              nullptr, nullptr, nullptr, out);
}